// Round 1
// baseline (663.855 us; speedup 1.0000x reference)
//
#include <hip/hip_runtime.h>
#include <hip/hip_bf16.h>
#include <math.h>

#define NN 50000
#define EDGES 1600000
#define ETOT (EDGES + NN)
#define FINDIM 39
#define NPART 256
#define PSZ 196        // dsts per partition; 256*196 = 50176 >= NN
#define PCAP 7100      // capacity per partition (avg 6468, +7.9 sigma)
#define P1TILE 4096

__device__ __forceinline__ unsigned pack_bf16(float a, float b) {
    __hip_bfloat162 t;
    t.x = __float2bfloat16(a);
    t.y = __float2bfloat16(b);
    return *(unsigned*)&t;
}
__device__ __forceinline__ float2 unpack_bf16(unsigned w) {
    float2 r;
    r.x = __uint_as_float(w << 16);
    r.y = __uint_as_float(w & 0xffff0000u);
    return r;
}

__device__ __forceinline__ int src_at(const int* ei, int i, bool i32) {
    return i32 ? ei[i] : ei[2 * i];
}
__device__ __forceinline__ int dst_at(const int* ei, int i, bool i32) {
    return i32 ? ei[EDGES + i] : ei[2 * (EDGES + i)];
}

// ---------------- CSR pass 1 (self-detecting int32/int64): bucket into 256 partitions ----------------
__global__ __launch_bounds__(256) void pass1_kernel(const int* __restrict__ ei,
                                                    int* __restrict__ gcursor,
                                                    unsigned* __restrict__ pbuf) {
    __shared__ unsigned raw[P1TILE];
    __shared__ unsigned srt[P1TILE];
    __shared__ int pcnt[NPART], poff[NPART], pcur[NPART], gb[NPART];
    __shared__ int i32flag;
    int t = threadIdx.x;
    if (t == 0) i32flag = 0;
    __syncthreads();
    int chunk = (ETOT + gridDim.x - 1) / gridDim.x;
    int c0 = blockIdx.x * chunk;
    int c1 = c0 + chunk; if (c1 > ETOT) c1 = ETOT;
    int sb = c0 < EDGES - 64 ? c0 : 0;
    if (t < 64 && ei[2 * (sb + t) + 1] != 0) i32flag = 1;
    __syncthreads();
    bool i32 = (i32flag != 0);
    for (int t0 = c0; t0 < c1; t0 += P1TILE) {
        int tn = c1 - t0; if (tn > P1TILE) tn = P1TILE;
        pcnt[t] = 0; pcur[t] = 0;
        __syncthreads();
        for (int i = t; i < tn; i += 256) {
            int e = t0 + i;
            int s, d;
            if (e < EDGES) { s = src_at(ei, e, i32); d = dst_at(ei, e, i32); }
            else { s = d = e - EDGES; }
            raw[i] = ((unsigned)s << 16) | (unsigned)d;
            atomicAdd(&pcnt[d / PSZ], 1);
        }
        __syncthreads();
        poff[t] = pcnt[t];
        __syncthreads();
        for (int off = 1; off < NPART; off <<= 1) {
            int v = (t >= off) ? poff[t - off] : 0;
            __syncthreads();
            poff[t] += v;
            __syncthreads();
        }
        poff[t] -= pcnt[t];                       // exclusive
        gb[t] = atomicAdd(&gcursor[t], pcnt[t]);  // global base for this tile's run
        __syncthreads();
        for (int i = t; i < tn; i += 256) {
            unsigned r = raw[i];
            int part = (int)(r & 0xFFFFu) / PSZ;
            int pos = poff[part] + atomicAdd(&pcur[part], 1);
            srt[pos] = r;
        }
        __syncthreads();
        for (int i = t; i < tn; i += 256) {
            unsigned r = srt[i];
            int part = (int)(r & 0xFFFFu) / PSZ;
            int gpos = gb[part] + (i - poff[part]);
            if (gpos < PCAP) pbuf[(size_t)part * PCAP + gpos] = r;
        }
        __syncthreads();
    }
}

// ---------------- CSR pass 2: per-partition exact sort -> rowptr + colidx (pbase inline) ----------------
__global__ __launch_bounds__(256) void pass2_kernel(const unsigned* __restrict__ pbuf,
                                                    const int* __restrict__ gcursor,
                                                    int* __restrict__ rowptr,
                                                    int* __restrict__ colidx) {
    __shared__ unsigned recs[PCAP];                 // 28.4 KB
    __shared__ int lhist[PSZ], lexcl[PSZ], lcur[PSZ];
    __shared__ int psm[NPART];
    int p = blockIdx.x;
    int t = threadIdx.x;
    // inline prefix over the 256 partition totals
    psm[t] = gcursor[t];
    __syncthreads();
    for (int off = 1; off < NPART; off <<= 1) {
        int x = (t >= off) ? psm[t - off] : 0;
        __syncthreads();
        psm[t] += x;
        __syncthreads();
    }
    int n = gcursor[p]; if (n > PCAP) n = PCAP;
    int base = psm[p] - gcursor[p];
    if (p == NPART - 1 && t == 0) rowptr[NN] = psm[NPART - 1];   // == ETOT
    int d0 = p * PSZ;
    int nd = NN - d0; if (nd > PSZ) nd = PSZ;
    if (nd < 0) nd = 0;
    for (int i = t; i < nd; i += 256) { lhist[i] = 0; lcur[i] = 0; }
    __syncthreads();
    for (int i = t; i < n; i += 256) {
        unsigned r = pbuf[(size_t)p * PCAP + i];
        recs[i] = r;
        atomicAdd(&lhist[(int)(r & 0xFFFFu) - d0], 1);
    }
    __syncthreads();
    for (int i = t; i < nd; i += 256) lexcl[i] = lhist[i];
    __syncthreads();
    for (int off = 1; off < PSZ; off <<= 1) {
        int a0 = 0;
        if (t < nd && t >= off) a0 = lexcl[t - off];
        __syncthreads();
        if (t < nd) lexcl[t] += a0;
        __syncthreads();
    }
    for (int i = t; i < nd; i += 256) {
        lexcl[i] -= lhist[i];                        // exclusive
        rowptr[d0 + i] = base + lexcl[i];
    }
    __syncthreads();
    for (int i = t; i < n; i += 256) {
        unsigned r = recs[i];
        int li = (int)(r & 0xFFFFu) - d0;
        int pos = base + lexcl[li] + atomicAdd(&lcur[li], 1);
        colidx[pos] = (int)(r >> 16);
    }
}

// ---------------- generic GEMM (K=39 encoder-1 only) ----------------
template <int NC, bool RELU>
__global__ __launch_bounds__(256) void gemm_small_kernel(const float* __restrict__ A,
                                                         const float* __restrict__ B,
                                                         const float* __restrict__ bias,
                                                         float* __restrict__ C, int M, int K) {
    constexpr int TM = 32;
    constexpr int GROUPS = 256 / NC;
    constexpr int RPG = TM / GROUPS;
    constexpr int KC = 64;
    __shared__ float As[TM * 128];
    __shared__ float Bs[KC * NC];
    int t = threadIdx.x;
    int i0 = blockIdx.x * TM;

    int rows = M - i0; if (rows > TM) rows = TM;
    for (int idx = t; idx < rows * K; idx += 256) {
        int r = idx / K, k = idx - r * K;
        As[r * K + k] = A[(size_t)(i0 + r) * K + k];
    }

    int col = t % NC, grp = t / NC;
    int rg0 = grp * RPG;
    float acc[RPG];
#pragma unroll
    for (int r = 0; r < RPG; ++r) acc[r] = 0.f;

    for (int k0 = 0; k0 < K; k0 += KC) {
        int kc = K - k0; if (kc > KC) kc = KC;
        __syncthreads();
        for (int idx = t; idx < kc * NC; idx += 256) Bs[idx] = B[(size_t)k0 * NC + idx];
        __syncthreads();
        for (int k = 0; k < kc; ++k) {
            float bv = Bs[k * NC + col];
#pragma unroll
            for (int r = 0; r < RPG; ++r) acc[r] += As[(rg0 + r) * K + k0 + k] * bv;
        }
    }

    float bb = bias ? bias[col] : 0.f;
#pragma unroll
    for (int r = 0; r < RPG; ++r) {
        int i = i0 + rg0 + r;
        if (i < M) {
            float v = acc[r] + bb;
            if (RELU) v = v > 0.f ? v : 0.f;
            C[(size_t)i * NC + col] = v;
        }
    }
}

// ---------------- fast GEMM 128x128, 24KB LDS; EPI: packed-bf16 xp + es/ed ----------------
template <bool BIAS, bool EPI>
__global__ __launch_bounds__(256) void gemm128_kernel(const float* __restrict__ A,
                                                      const float* __restrict__ B,
                                                      const float* __restrict__ bias,
                                                      float* __restrict__ C,
                                                      unsigned* __restrict__ XP,
                                                      const float* __restrict__ a_s,
                                                      const float* __restrict__ a_d,
                                                      float* __restrict__ es,
                                                      float* __restrict__ ed, int M) {
    __shared__ float As[64 * 32];    // 8 KB : 64 rows x 32-k chunk
    __shared__ float Bs[32 * 128];   // 16 KB: 32-k chunk x 128 cols
    int t = threadIdx.x;
    int i0 = blockIdx.x * 64;
    int tc = t & 31;                 // cols tc*4 .. tc*4+3
    int tr = t >> 5;
    int r0 = tr * 8;
    int c0 = tc * 4;

    float acc[8][4];
#pragma unroll
    for (int i = 0; i < 8; ++i)
#pragma unroll
        for (int j = 0; j < 4; ++j) acc[i][j] = 0.f;

    for (int k0 = 0; k0 < 128; k0 += 32) {
        __syncthreads();
#pragma unroll
        for (int q = 0; q < 2; ++q) {
            int idx = t + q * 256;           // 0..511
            int r = idx >> 3, kq = idx & 7;
            float4 v4 = make_float4(0.f, 0.f, 0.f, 0.f);
            if (i0 + r < M) v4 = *(const float4*)&A[(size_t)(i0 + r) * 128 + k0 + kq * 4];
            *(float4*)&As[r * 32 + kq * 4] = v4;
        }
#pragma unroll
        for (int q = 0; q < 4; ++q) {
            int idx = (t + q * 256) * 4;
            *(float4*)&Bs[idx] = *(const float4*)&B[(size_t)k0 * 128 + idx];
        }
        __syncthreads();
#pragma unroll 8
        for (int k = 0; k < 32; k += 4) {
            float4 a4[8];
#pragma unroll
            for (int i = 0; i < 8; ++i)
                a4[i] = *(const float4*)&As[(r0 + i) * 32 + k];
            float4 b4[4];
#pragma unroll
            for (int kk = 0; kk < 4; ++kk)
                b4[kk] = *(const float4*)&Bs[(k + kk) * 128 + c0];
#pragma unroll
            for (int i = 0; i < 8; ++i) {
                const float* av = (const float*)&a4[i];
#pragma unroll
                for (int kk = 0; kk < 4; ++kk) {
                    acc[i][0] += av[kk] * b4[kk].x;
                    acc[i][1] += av[kk] * b4[kk].y;
                    acc[i][2] += av[kk] * b4[kk].z;
                    acc[i][3] += av[kk] * b4[kk].w;
                }
            }
        }
    }

    if (!EPI) {
        float4 bias4 = make_float4(0.f, 0.f, 0.f, 0.f);
        if (BIAS) bias4 = *(const float4*)&bias[c0];
#pragma unroll
        for (int i = 0; i < 8; ++i) {
            int row = i0 + r0 + i;
            if (row < M) {
                float4 o;
                o.x = acc[i][0] + bias4.x;
                o.y = acc[i][1] + bias4.y;
                o.z = acc[i][2] + bias4.z;
                o.w = acc[i][3] + bias4.w;
                *(float4*)&C[(size_t)row * 128 + c0] = o;
            }
        }
    } else {
#pragma unroll
        for (int i = 0; i < 8; ++i) {
            int row = i0 + r0 + i;
            if (row < M) {
                uint2 o;
                o.x = pack_bf16(acc[i][0], acc[i][1]);
                o.y = pack_bf16(acc[i][2], acc[i][3]);
                *(uint2*)&XP[(size_t)row * 64 + tc * 2] = o;
            }
        }
        int hd = tc >> 3;
        float4 s4 = *(const float4*)&a_s[c0];
        float4 d4 = *(const float4*)&a_d[c0];
#pragma unroll
        for (int i = 0; i < 8; ++i) {
            int row = i0 + r0 + i;
            float s = acc[i][0] * s4.x + acc[i][1] * s4.y + acc[i][2] * s4.z + acc[i][3] * s4.w;
            float d = acc[i][0] * d4.x + acc[i][1] * d4.y + acc[i][2] * d4.z + acc[i][3] * d4.w;
#pragma unroll
            for (int off = 4; off >= 1; off >>= 1) {
                s += __shfl_xor(s, off);
                d += __shfl_xor(d, off);
            }
            if ((tc & 7) == 0 && row < M) {
                es[row * 4 + hd] = s;
                ed[row * 4 + hd] = d;
            }
        }
    }
}

// ---------------- head GEMMs fully fused: h -> out (impact+timing), 24KB LDS ----------------
__global__ __launch_bounds__(256) void gemm_heads_kernel(const float* __restrict__ A,
                                                         const float* __restrict__ iw1,
                                                         const float* __restrict__ ib1,
                                                         const float* __restrict__ tw1,
                                                         const float* __restrict__ tb1,
                                                         const float* __restrict__ iw2,
                                                         const float* __restrict__ ib2,
                                                         const float* __restrict__ tw2,
                                                         const float* __restrict__ tb2,
                                                         float* __restrict__ out, int M) {
    __shared__ float As[64 * 32];
    __shared__ float Bs[32 * 128];
    int t = threadIdx.x;
    int i0 = blockIdx.x * 64;
    int tc = t & 31;
    int tr = t >> 5;
    int r0 = tr * 8;
    int c0 = tc * 4;                 // virtual col (0-63 impact, 64-127 timing)

    float acc[8][4];
#pragma unroll
    for (int i = 0; i < 8; ++i)
#pragma unroll
        for (int j = 0; j < 4; ++j) acc[i][j] = 0.f;

    for (int k0 = 0; k0 < 128; k0 += 32) {
        __syncthreads();
#pragma unroll
        for (int q = 0; q < 2; ++q) {
            int idx = t + q * 256;
            int r = idx >> 3, kq = idx & 7;
            float4 v4 = make_float4(0.f, 0.f, 0.f, 0.f);
            if (i0 + r < M) v4 = *(const float4*)&A[(size_t)(i0 + r) * 128 + k0 + kq * 4];
            *(float4*)&As[r * 32 + kq * 4] = v4;
        }
#pragma unroll
        for (int q = 0; q < 4; ++q) {
            int idx = (t + q * 256) * 4;       // flat into [32][128]
            int k = idx >> 7, cl = idx & 127;
            float4 v4 = (cl < 64)
                ? *(const float4*)&iw1[(size_t)(k0 + k) * 64 + cl]
                : *(const float4*)&tw1[(size_t)(k0 + k) * 64 + (cl - 64)];
            *(float4*)&Bs[idx] = v4;
        }
        __syncthreads();
#pragma unroll 8
        for (int k = 0; k < 32; k += 4) {
            float4 a4[8];
#pragma unroll
            for (int i = 0; i < 8; ++i)
                a4[i] = *(const float4*)&As[(r0 + i) * 32 + k];
            float4 b4[4];
#pragma unroll
            for (int kk = 0; kk < 4; ++kk)
                b4[kk] = *(const float4*)&Bs[(k + kk) * 128 + c0];
#pragma unroll
            for (int i = 0; i < 8; ++i) {
                const float* av = (const float*)&a4[i];
#pragma unroll
                for (int kk = 0; kk < 4; ++kk) {
                    acc[i][0] += av[kk] * b4[kk].x;
                    acc[i][1] += av[kk] * b4[kk].y;
                    acc[i][2] += av[kk] * b4[kk].z;
                    acc[i][3] += av[kk] * b4[kk].w;
                }
            }
        }
    }

    bool isimp = (tc < 16);
    int lc = isimp ? c0 : (c0 - 64);
    float v[8][4];
#pragma unroll
    for (int i = 0; i < 8; ++i)
#pragma unroll
        for (int j = 0; j < 4; ++j) {
            float b = isimp ? ib1[lc + j] : tb1[lc + j];
            float x = acc[i][j] + b;
            v[i][j] = x > 0.f ? x : 0.f;
        }
#pragma unroll
    for (int i = 0; i < 8; ++i) {
        int row = i0 + r0 + i;
        if (isimp) {
#pragma unroll
            for (int c = 0; c < 3; ++c) {
                float pc = v[i][0] * iw2[(lc + 0) * 3 + c] + v[i][1] * iw2[(lc + 1) * 3 + c]
                         + v[i][2] * iw2[(lc + 2) * 3 + c] + v[i][3] * iw2[(lc + 3) * 3 + c];
#pragma unroll
                for (int off = 8; off >= 1; off >>= 1) pc += __shfl_xor(pc, off);
                if (tc == 0 && row < M) out[(size_t)row * 3 + c] = pc + ib2[c];
            }
        } else {
#pragma unroll
            for (int d = 0; d < 2; ++d) {
                float pd = v[i][0] * tw2[(lc + 0) * 2 + d] + v[i][1] * tw2[(lc + 1) * 2 + d]
                         + v[i][2] * tw2[(lc + 2) * 2 + d] + v[i][3] * tw2[(lc + 3) * 2 + d];
#pragma unroll
                for (int off = 8; off >= 1; off >>= 1) pd += __shfl_xor(pd, off);
                if (tc == 16 && row < M) {
                    float a = pd + tb2[d];
                    float sp = a > 20.f ? a : log1pf(__expf(a));
                    out[(size_t)(NN * 3) + (size_t)row * 2 + d] = sp;
                }
            }
        }
    }
}

// ---------------- gat v7: lane-parallel attention weights (1 exp / 8 edges), bpermute
// broadcast, masked tail (needs 8 zeroed pad ints after colidx).
// Lane l: head hq = l&3, within-head pair j = l>>2  -> channels c0 = hq*32 + 2j.
// w-phase: lane computes w for edge slot (l&31)>>2, head l&3 (lanes 32-63 duplicate).
__global__ __launch_bounds__(256) void gat_kernel(const unsigned* __restrict__ xpk,
                                                  const float* __restrict__ es,
                                                  const float* __restrict__ ed,
                                                  const int* __restrict__ rowptr,
                                                  const int* __restrict__ colidx,
                                                  float* __restrict__ h,   // in-out (residual)
                                                  const float* __restrict__ bc,
                                                  const float* __restrict__ g,
                                                  const float* __restrict__ be) {
    int wv = threadIdx.x >> 6, l = threadIdx.x & 63;
    int v = blockIdx.x * 4 + wv;
    if (v >= NN) return;
    int s0 = rowptr[v], s1 = rowptr[v + 1];
    int hq = l & 3;                        // this lane's head (both phases)
    int j = l >> 2;                        // within-head pair index 0..15
    int qlane = (l & 31) >> 2;             // edge slot whose weight this lane computes
    int xsel = (hq << 4) + j;              // dword index within a 64-dword xpk row
    int wsel = hq << 2;                    // bpermute byte base: src lane = 4q + hq
    float edv = ed[(unsigned)(v << 2) + hq];

    float ax = 0.f, ay = 0.f, denp = 0.f;  // denp: partial denom for (slot qlane, head hq)
    for (int p = s0; p < s1; p += 8) {
        int rr = s1 - p;                   // >=1; slots >= rr masked to w=0
        int u[8];
#pragma unroll
        for (int q = 0; q < 8; ++q) u[q] = colidx[p + q];   // wave-uniform broadcast loads
        int ul = colidx[p + qlane];        // per-lane edge for w-phase (same cache line)
        float ev = es[((unsigned)ul << 2) + hq] + edv;
        ev = fmaxf(ev, 0.2f * ev);         // leaky_relu, slope<1 => max form
        float w = (qlane < rr) ? __expf(ev) : 0.f;   // no max-shift: softmax shift-invariant
        denp += w;
#pragma unroll
        for (int q = 0; q < 8; ++q) {
            float wq = __int_as_float(
                __builtin_amdgcn_ds_bpermute(wsel + (q << 4), __float_as_int(w)));
            float2 x = unpack_bf16(xpk[((unsigned)u[q] << 6) + xsel]);
            ax = fmaf(wq, x.x, ax);
            ay = fmaf(wq, x.y, ay);
        }
    }
    // denom for head hq = sum over the 8 slot-lanes {hq + 4q}: xor-reduce bits 2..4
#pragma unroll
    for (int off = 4; off <= 16; off <<= 1) denp += __shfl_xor(denp, off);
    float rd = 1.f / denp;

    int c0 = (hq << 5) + (j << 1);         // channel pair this lane owns
    float2 h2  = *(const float2*)&h[(size_t)v * 128 + c0];
    float2 bc2 = *(const float2*)&bc[c0];
    float y0 = ax * rd + bc2.x + h2.x;
    float y1 = ay * rd + bc2.y + h2.y;

    float s = y0 + y1;
#pragma unroll
    for (int off = 32; off >= 1; off >>= 1) s += __shfl_xor(s, off);
    float mean = s * (1.f / 128.f);
    float d0 = y0 - mean, d1 = y1 - mean;
    float vv = d0 * d0 + d1 * d1;
#pragma unroll
    for (int off = 32; off >= 1; off >>= 1) vv += __shfl_xor(vv, off);
    float rstd = rsqrtf(vv * (1.f / 128.f) + 1e-5f);
    float2 g2  = *(const float2*)&g[c0];
    float2 be2 = *(const float2*)&be[c0];
    float z0 = d0 * rstd * g2.x + be2.x;
    float z1 = d1 * rstd * g2.y + be2.y;
    float2 o;
    o.x = z0 > 0.f ? z0 : 0.f;
    o.y = z1 > 0.f ? z1 : 0.f;
    *(float2*)&h[(size_t)v * 128 + c0] = o;
}

extern "C" void kernel_launch(void* const* d_in, const int* in_sizes, int n_in,
                              void* d_out, int out_size, void* d_ws, size_t ws_size,
                              hipStream_t stream) {
    const float* x      = (const float*)d_in[0];
    const int*   ei     = (const int*)d_in[1];
    const float* enc_w1 = (const float*)d_in[2];
    const float* enc_b1 = (const float*)d_in[3];
    const float* enc_w2 = (const float*)d_in[4];
    const float* enc_b2 = (const float*)d_in[5];
    const float *W[3], *as_[3], *ad_[3], *bc[3], *g[3], *be[3];
    for (int l = 0; l < 3; ++l) {
        W[l]   = (const float*)d_in[6 + l * 6 + 0];
        as_[l] = (const float*)d_in[6 + l * 6 + 1];
        ad_[l] = (const float*)d_in[6 + l * 6 + 2];
        bc[l]  = (const float*)d_in[6 + l * 6 + 3];
        g[l]   = (const float*)d_in[6 + l * 6 + 4];
        be[l]  = (const float*)d_in[6 + l * 6 + 5];
    }
    const float* imp_w1 = (const float*)d_in[24];
    const float* imp_b1 = (const float*)d_in[25];
    const float* imp_w2 = (const float*)d_in[26];
    const float* imp_b2 = (const float*)d_in[27];
    const float* tim_w1 = (const float*)d_in[28];
    const float* tim_b1 = (const float*)d_in[29];
    const float* tim_w2 = (const float*)d_in[30];
    const float* tim_b2 = (const float*)d_in[31];

    int* gcursor = (int*)d_ws;               // NPART
    int* rowptr  = gcursor + NPART + 64;     // NN+1
    int* colidx  = rowptr + NN + 1;          // ETOT + 8 pad
    uintptr_t pb = (uintptr_t)(colidx + ETOT + 8);
    pb = (pb + 255) & ~(uintptr_t)255;
    unsigned* pbuf = (unsigned*)pb;          // NPART*PCAP (7.3 MB)
    uintptr_t fb = (uintptr_t)(pbuf + (size_t)NPART * PCAP);
    fb = (fb + 255) & ~(uintptr_t)255;
    float* es = (float*)fb;                  // NN*4
    float* ed = es + (size_t)NN * 4;         // NN*4
    float* h  = ed + (size_t)NN * 4;         // NN*128 fp32
    float* xpf = h + (size_t)NN * 128;       // region sized NN*128 floats
    unsigned* xpk = (unsigned*)xpf;          // packed bf16 uses first half
    float* tmp = xpf;                        // enc1 scratch aliases (dead before xpk lives)

    hipMemsetAsync(gcursor, 0, NPART * sizeof(int), stream);
    hipMemsetAsync(colidx + ETOT, 0, 8 * sizeof(int), stream);  // pad for masked tail reads
    pass1_kernel<<<512, 256, 0, stream>>>(ei, gcursor, pbuf);
    pass2_kernel<<<NPART, 256, 0, stream>>>(pbuf, gcursor, rowptr, colidx);

    const int GB64 = (NN + 63) / 64;
    gemm_small_kernel<128, true><<<(NN + 31) / 32, 256, 0, stream>>>(x, enc_w1, enc_b1, tmp, NN, FINDIM);
    gemm128_kernel<true, false><<<GB64, 256, 0, stream>>>(tmp, enc_w2, enc_b2, h, nullptr,
                                                          nullptr, nullptr, nullptr, nullptr, NN);

    for (int l = 0; l < 3; ++l) {
        gemm128_kernel<false, true><<<GB64, 256, 0, stream>>>(h, W[l], nullptr, nullptr, xpk,
                                                              as_[l], ad_[l], es, ed, NN);
        gat_kernel<<<(NN + 3) / 4, 256, 0, stream>>>(xpk, es, ed, rowptr, colidx, h,
                                                     bc[l], g[l], be[l]);
    }

    gemm_heads_kernel<<<GB64, 256, 0, stream>>>(h, imp_w1, imp_b1, tim_w1, tim_b1,
                                                imp_w2, imp_b2, tim_w2, tim_b2,
                                                (float*)d_out, NN);
}

// Round 2
// 609.508 us; speedup vs baseline: 1.0892x; 1.0892x over previous
//
#include <hip/hip_runtime.h>
#include <hip/hip_bf16.h>
#include <math.h>

#define NN 50000
#define EDGES 1600000
#define ETOT (EDGES + NN)
#define FINDIM 39
#define NPART 256
#define PSZ 196        // dsts per partition; 256*196 = 50176 >= NN
#define PCAP 7100      // capacity per partition (avg 6468, +7.9 sigma)
#define P1TILE 4096
#define MAXS 128       // max row length on fast path (avg 33, max ~70 for this data)
#define SLOTW 9        // dwords per slot in LDS: w[4] at +hq, u (dup x4) at +4+hq, +1 pad

__device__ __forceinline__ unsigned pack_bf16(float a, float b) {
    __hip_bfloat162 t;
    t.x = __float2bfloat16(a);
    t.y = __float2bfloat16(b);
    return *(unsigned*)&t;
}
__device__ __forceinline__ float2 unpack_bf16(unsigned w) {
    float2 r;
    r.x = __uint_as_float(w << 16);
    r.y = __uint_as_float(w & 0xffff0000u);
    return r;
}

__device__ __forceinline__ int src_at(const int* ei, int i, bool i32) {
    return i32 ? ei[i] : ei[2 * i];
}
__device__ __forceinline__ int dst_at(const int* ei, int i, bool i32) {
    return i32 ? ei[EDGES + i] : ei[2 * (EDGES + i)];
}

// ---------------- CSR pass 1 (self-detecting int32/int64): bucket into 256 partitions ----------------
__global__ __launch_bounds__(256) void pass1_kernel(const int* __restrict__ ei,
                                                    int* __restrict__ gcursor,
                                                    unsigned* __restrict__ pbuf) {
    __shared__ unsigned raw[P1TILE];
    __shared__ unsigned srt[P1TILE];
    __shared__ int pcnt[NPART], poff[NPART], pcur[NPART], gb[NPART];
    __shared__ int i32flag;
    int t = threadIdx.x;
    if (t == 0) i32flag = 0;
    __syncthreads();
    int chunk = (ETOT + gridDim.x - 1) / gridDim.x;
    int c0 = blockIdx.x * chunk;
    int c1 = c0 + chunk; if (c1 > ETOT) c1 = ETOT;
    int sb = c0 < EDGES - 64 ? c0 : 0;
    if (t < 64 && ei[2 * (sb + t) + 1] != 0) i32flag = 1;
    __syncthreads();
    bool i32 = (i32flag != 0);
    for (int t0 = c0; t0 < c1; t0 += P1TILE) {
        int tn = c1 - t0; if (tn > P1TILE) tn = P1TILE;
        pcnt[t] = 0; pcur[t] = 0;
        __syncthreads();
        for (int i = t; i < tn; i += 256) {
            int e = t0 + i;
            int s, d;
            if (e < EDGES) { s = src_at(ei, e, i32); d = dst_at(ei, e, i32); }
            else { s = d = e - EDGES; }
            raw[i] = ((unsigned)s << 16) | (unsigned)d;
            atomicAdd(&pcnt[d / PSZ], 1);
        }
        __syncthreads();
        poff[t] = pcnt[t];
        __syncthreads();
        for (int off = 1; off < NPART; off <<= 1) {
            int v = (t >= off) ? poff[t - off] : 0;
            __syncthreads();
            poff[t] += v;
            __syncthreads();
        }
        poff[t] -= pcnt[t];                       // exclusive
        gb[t] = atomicAdd(&gcursor[t], pcnt[t]);  // global base for this tile's run
        __syncthreads();
        for (int i = t; i < tn; i += 256) {
            unsigned r = raw[i];
            int part = (int)(r & 0xFFFFu) / PSZ;
            int pos = poff[part] + atomicAdd(&pcur[part], 1);
            srt[pos] = r;
        }
        __syncthreads();
        for (int i = t; i < tn; i += 256) {
            unsigned r = srt[i];
            int part = (int)(r & 0xFFFFu) / PSZ;
            int gpos = gb[part] + (i - poff[part]);
            if (gpos < PCAP) pbuf[(size_t)part * PCAP + gpos] = r;
        }
        __syncthreads();
    }
}

// ---------------- CSR pass 2: per-partition exact sort -> rowptr + colidx (pbase inline) ----------------
__global__ __launch_bounds__(256) void pass2_kernel(const unsigned* __restrict__ pbuf,
                                                    const int* __restrict__ gcursor,
                                                    int* __restrict__ rowptr,
                                                    int* __restrict__ colidx) {
    __shared__ unsigned recs[PCAP];                 // 28.4 KB
    __shared__ int lhist[PSZ], lexcl[PSZ], lcur[PSZ];
    __shared__ int psm[NPART];
    int p = blockIdx.x;
    int t = threadIdx.x;
    // inline prefix over the 256 partition totals
    psm[t] = gcursor[t];
    __syncthreads();
    for (int off = 1; off < NPART; off <<= 1) {
        int x = (t >= off) ? psm[t - off] : 0;
        __syncthreads();
        psm[t] += x;
        __syncthreads();
    }
    int n = gcursor[p]; if (n > PCAP) n = PCAP;
    int base = psm[p] - gcursor[p];
    if (p == NPART - 1 && t == 0) rowptr[NN] = psm[NPART - 1];   // == ETOT
    int d0 = p * PSZ;
    int nd = NN - d0; if (nd > PSZ) nd = PSZ;
    if (nd < 0) nd = 0;
    for (int i = t; i < nd; i += 256) { lhist[i] = 0; lcur[i] = 0; }
    __syncthreads();
    for (int i = t; i < n; i += 256) {
        unsigned r = pbuf[(size_t)p * PCAP + i];
        recs[i] = r;
        atomicAdd(&lhist[(int)(r & 0xFFFFu) - d0], 1);
    }
    __syncthreads();
    for (int i = t; i < nd; i += 256) lexcl[i] = lhist[i];
    __syncthreads();
    for (int off = 1; off < PSZ; off <<= 1) {
        int a0 = 0;
        if (t < nd && t >= off) a0 = lexcl[t - off];
        __syncthreads();
        if (t < nd) lexcl[t] += a0;
        __syncthreads();
    }
    for (int i = t; i < nd; i += 256) {
        lexcl[i] -= lhist[i];                        // exclusive
        rowptr[d0 + i] = base + lexcl[i];
    }
    __syncthreads();
    for (int i = t; i < n; i += 256) {
        unsigned r = recs[i];
        int li = (int)(r & 0xFFFFu) - d0;
        int pos = base + lexcl[li] + atomicAdd(&lcur[li], 1);
        colidx[pos] = (int)(r >> 16);
    }
}

// ---------------- generic GEMM (K=39 encoder-1 only) ----------------
template <int NC, bool RELU>
__global__ __launch_bounds__(256) void gemm_small_kernel(const float* __restrict__ A,
                                                         const float* __restrict__ B,
                                                         const float* __restrict__ bias,
                                                         float* __restrict__ C, int M, int K) {
    constexpr int TM = 32;
    constexpr int GROUPS = 256 / NC;
    constexpr int RPG = TM / GROUPS;
    constexpr int KC = 64;
    __shared__ float As[TM * 128];
    __shared__ float Bs[KC * NC];
    int t = threadIdx.x;
    int i0 = blockIdx.x * TM;

    int rows = M - i0; if (rows > TM) rows = TM;
    for (int idx = t; idx < rows * K; idx += 256) {
        int r = idx / K, k = idx - r * K;
        As[r * K + k] = A[(size_t)(i0 + r) * K + k];
    }

    int col = t % NC, grp = t / NC;
    int rg0 = grp * RPG;
    float acc[RPG];
#pragma unroll
    for (int r = 0; r < RPG; ++r) acc[r] = 0.f;

    for (int k0 = 0; k0 < K; k0 += KC) {
        int kc = K - k0; if (kc > KC) kc = KC;
        __syncthreads();
        for (int idx = t; idx < kc * NC; idx += 256) Bs[idx] = B[(size_t)k0 * NC + idx];
        __syncthreads();
        for (int k = 0; k < kc; ++k) {
            float bv = Bs[k * NC + col];
#pragma unroll
            for (int r = 0; r < RPG; ++r) acc[r] += As[(rg0 + r) * K + k0 + k] * bv;
        }
    }

    float bb = bias ? bias[col] : 0.f;
#pragma unroll
    for (int r = 0; r < RPG; ++r) {
        int i = i0 + rg0 + r;
        if (i < M) {
            float v = acc[r] + bb;
            if (RELU) v = v > 0.f ? v : 0.f;
            C[(size_t)i * NC + col] = v;
        }
    }
}

// ---------------- fast GEMM 128x128, 24KB LDS; EPI: packed-bf16 xp + es/ed ----------------
template <bool BIAS, bool EPI>
__global__ __launch_bounds__(256) void gemm128_kernel(const float* __restrict__ A,
                                                      const float* __restrict__ B,
                                                      const float* __restrict__ bias,
                                                      float* __restrict__ C,
                                                      unsigned* __restrict__ XP,
                                                      const float* __restrict__ a_s,
                                                      const float* __restrict__ a_d,
                                                      float* __restrict__ es,
                                                      float* __restrict__ ed, int M) {
    __shared__ float As[64 * 32];    // 8 KB : 64 rows x 32-k chunk
    __shared__ float Bs[32 * 128];   // 16 KB: 32-k chunk x 128 cols
    int t = threadIdx.x;
    int i0 = blockIdx.x * 64;
    int tc = t & 31;                 // cols tc*4 .. tc*4+3
    int tr = t >> 5;
    int r0 = tr * 8;
    int c0 = tc * 4;

    float acc[8][4];
#pragma unroll
    for (int i = 0; i < 8; ++i)
#pragma unroll
        for (int j = 0; j < 4; ++j) acc[i][j] = 0.f;

    for (int k0 = 0; k0 < 128; k0 += 32) {
        __syncthreads();
#pragma unroll
        for (int q = 0; q < 2; ++q) {
            int idx = t + q * 256;           // 0..511
            int r = idx >> 3, kq = idx & 7;
            float4 v4 = make_float4(0.f, 0.f, 0.f, 0.f);
            if (i0 + r < M) v4 = *(const float4*)&A[(size_t)(i0 + r) * 128 + k0 + kq * 4];
            *(float4*)&As[r * 32 + kq * 4] = v4;
        }
#pragma unroll
        for (int q = 0; q < 4; ++q) {
            int idx = (t + q * 256) * 4;
            *(float4*)&Bs[idx] = *(const float4*)&B[(size_t)k0 * 128 + idx];
        }
        __syncthreads();
#pragma unroll 8
        for (int k = 0; k < 32; k += 4) {
            float4 a4[8];
#pragma unroll
            for (int i = 0; i < 8; ++i)
                a4[i] = *(const float4*)&As[(r0 + i) * 32 + k];
            float4 b4[4];
#pragma unroll
            for (int kk = 0; kk < 4; ++kk)
                b4[kk] = *(const float4*)&Bs[(k + kk) * 128 + c0];
#pragma unroll
            for (int i = 0; i < 8; ++i) {
                const float* av = (const float*)&a4[i];
#pragma unroll
                for (int kk = 0; kk < 4; ++kk) {
                    acc[i][0] += av[kk] * b4[kk].x;
                    acc[i][1] += av[kk] * b4[kk].y;
                    acc[i][2] += av[kk] * b4[kk].z;
                    acc[i][3] += av[kk] * b4[kk].w;
                }
            }
        }
    }

    if (!EPI) {
        float4 bias4 = make_float4(0.f, 0.f, 0.f, 0.f);
        if (BIAS) bias4 = *(const float4*)&bias[c0];
#pragma unroll
        for (int i = 0; i < 8; ++i) {
            int row = i0 + r0 + i;
            if (row < M) {
                float4 o;
                o.x = acc[i][0] + bias4.x;
                o.y = acc[i][1] + bias4.y;
                o.z = acc[i][2] + bias4.z;
                o.w = acc[i][3] + bias4.w;
                *(float4*)&C[(size_t)row * 128 + c0] = o;
            }
        }
    } else {
#pragma unroll
        for (int i = 0; i < 8; ++i) {
            int row = i0 + r0 + i;
            if (row < M) {
                uint2 o;
                o.x = pack_bf16(acc[i][0], acc[i][1]);
                o.y = pack_bf16(acc[i][2], acc[i][3]);
                *(uint2*)&XP[(size_t)row * 64 + tc * 2] = o;
            }
        }
        int hd = tc >> 3;
        float4 s4 = *(const float4*)&a_s[c0];
        float4 d4 = *(const float4*)&a_d[c0];
#pragma unroll
        for (int i = 0; i < 8; ++i) {
            int row = i0 + r0 + i;
            float s = acc[i][0] * s4.x + acc[i][1] * s4.y + acc[i][2] * s4.z + acc[i][3] * s4.w;
            float d = acc[i][0] * d4.x + acc[i][1] * d4.y + acc[i][2] * d4.z + acc[i][3] * d4.w;
#pragma unroll
            for (int off = 4; off >= 1; off >>= 1) {
                s += __shfl_xor(s, off);
                d += __shfl_xor(d, off);
            }
            if ((tc & 7) == 0 && row < M) {
                es[row * 4 + hd] = s;
                ed[row * 4 + hd] = d;
            }
        }
    }
}

// ---------------- head GEMMs fully fused: h -> out (impact+timing), 24KB LDS ----------------
__global__ __launch_bounds__(256) void gemm_heads_kernel(const float* __restrict__ A,
                                                         const float* __restrict__ iw1,
                                                         const float* __restrict__ ib1,
                                                         const float* __restrict__ tw1,
                                                         const float* __restrict__ tb1,
                                                         const float* __restrict__ iw2,
                                                         const float* __restrict__ ib2,
                                                         const float* __restrict__ tw2,
                                                         const float* __restrict__ tb2,
                                                         float* __restrict__ out, int M) {
    __shared__ float As[64 * 32];
    __shared__ float Bs[32 * 128];
    int t = threadIdx.x;
    int i0 = blockIdx.x * 64;
    int tc = t & 31;
    int tr = t >> 5;
    int r0 = tr * 8;
    int c0 = tc * 4;                 // virtual col (0-63 impact, 64-127 timing)

    float acc[8][4];
#pragma unroll
    for (int i = 0; i < 8; ++i)
#pragma unroll
        for (int j = 0; j < 4; ++j) acc[i][j] = 0.f;

    for (int k0 = 0; k0 < 128; k0 += 32) {
        __syncthreads();
#pragma unroll
        for (int q = 0; q < 2; ++q) {
            int idx = t + q * 256;
            int r = idx >> 3, kq = idx & 7;
            float4 v4 = make_float4(0.f, 0.f, 0.f, 0.f);
            if (i0 + r < M) v4 = *(const float4*)&A[(size_t)(i0 + r) * 128 + k0 + kq * 4];
            *(float4*)&As[r * 32 + kq * 4] = v4;
        }
#pragma unroll
        for (int q = 0; q < 4; ++q) {
            int idx = (t + q * 256) * 4;       // flat into [32][128]
            int k = idx >> 7, cl = idx & 127;
            float4 v4 = (cl < 64)
                ? *(const float4*)&iw1[(size_t)(k0 + k) * 64 + cl]
                : *(const float4*)&tw1[(size_t)(k0 + k) * 64 + (cl - 64)];
            *(float4*)&Bs[idx] = v4;
        }
        __syncthreads();
#pragma unroll 8
        for (int k = 0; k < 32; k += 4) {
            float4 a4[8];
#pragma unroll
            for (int i = 0; i < 8; ++i)
                a4[i] = *(const float4*)&As[(r0 + i) * 32 + k];
            float4 b4[4];
#pragma unroll
            for (int kk = 0; kk < 4; ++kk)
                b4[kk] = *(const float4*)&Bs[(k + kk) * 128 + c0];
#pragma unroll
            for (int i = 0; i < 8; ++i) {
                const float* av = (const float*)&a4[i];
#pragma unroll
                for (int kk = 0; kk < 4; ++kk) {
                    acc[i][0] += av[kk] * b4[kk].x;
                    acc[i][1] += av[kk] * b4[kk].y;
                    acc[i][2] += av[kk] * b4[kk].z;
                    acc[i][3] += av[kk] * b4[kk].w;
                }
            }
        }
    }

    bool isimp = (tc < 16);
    int lc = isimp ? c0 : (c0 - 64);
    float v[8][4];
#pragma unroll
    for (int i = 0; i < 8; ++i)
#pragma unroll
        for (int j = 0; j < 4; ++j) {
            float b = isimp ? ib1[lc + j] : tb1[lc + j];
            float x = acc[i][j] + b;
            v[i][j] = x > 0.f ? x : 0.f;
        }
#pragma unroll
    for (int i = 0; i < 8; ++i) {
        int row = i0 + r0 + i;
        if (isimp) {
#pragma unroll
            for (int c = 0; c < 3; ++c) {
                float pc = v[i][0] * iw2[(lc + 0) * 3 + c] + v[i][1] * iw2[(lc + 1) * 3 + c]
                         + v[i][2] * iw2[(lc + 2) * 3 + c] + v[i][3] * iw2[(lc + 3) * 3 + c];
#pragma unroll
                for (int off = 8; off >= 1; off >>= 1) pc += __shfl_xor(pc, off);
                if (tc == 0 && row < M) out[(size_t)row * 3 + c] = pc + ib2[c];
            }
        } else {
#pragma unroll
            for (int d = 0; d < 2; ++d) {
                float pd = v[i][0] * tw2[(lc + 0) * 2 + d] + v[i][1] * tw2[(lc + 1) * 2 + d]
                         + v[i][2] * tw2[(lc + 2) * 2 + d] + v[i][3] * tw2[(lc + 3) * 2 + d];
#pragma unroll
                for (int off = 8; off >= 1; off >>= 1) pd += __shfl_xor(pd, off);
                if (tc == 16 && row < M) {
                    float a = pd + tb2[d];
                    float sp = a > 20.f ? a : log1pf(__expf(a));
                    out[(size_t)(NN * 3) + (size_t)row * 2 + d] = sp;
                }
            }
        }
    }
}

// ---------------- gat v8: two-phase. Phase 1 computes each weight ONCE (lane-parallel,
// 16 edges x 4 heads per iter) into a per-wave LDS table {w[4], u(dup x4)} per slot.
// Phase 2 is a pure MAC loop: ds_read2 (w+u) -> uint2 xpk gather -> 4 fma; each lane
// owns 4 channels, wave halves split even/odd edge slots. No exp/es-gather/bpermute
// on the FMA critical path (the v7 latency trap). Rows > MAXS take a slow fallback.
__global__ __launch_bounds__(256) void gat_kernel(const unsigned* __restrict__ xpk,
                                                  const float* __restrict__ es,
                                                  const float* __restrict__ ed,
                                                  const int* __restrict__ rowptr,
                                                  const int* __restrict__ colidx,
                                                  float* __restrict__ h,   // in-out (residual)
                                                  const float* __restrict__ bc,
                                                  const float* __restrict__ g,
                                                  const float* __restrict__ be) {
    __shared__ float wl[4][MAXS * SLOTW];   // 4 waves x 4.5 KB = 18 KB
    int wv = threadIdx.x >> 6, l = threadIdx.x & 63;
    int v = blockIdx.x * 4 + wv;
    if (v >= NN) return;
    int s0 = rowptr[v], s1 = rowptr[v + 1];
    int rowlen = s1 - s0;
    int hq = l & 3;                         // head (same in both phases & epilogue)
    int hf = l >> 5;                        // wave half: even/odd edge slots
    int j2 = (l & 31) >> 2;                 // 0..7 within-head quad index
    int c0 = (hq << 5) + (j2 << 2);         // 4 channels owned by this lane
    int xsel = (hq << 4) + (j2 << 1);       // even dword index into 64-dword xpk row
    float edv = ed[((unsigned)v << 2) + hq];
    float* wbase = wl[wv];

    float a0 = 0.f, a1 = 0.f, a2 = 0.f, a3 = 0.f;
    float den = 0.f;

    if (rowlen <= MAXS) {
        int npad = (rowlen + 7) & ~7;
        // ---- phase 1: weight table. lane -> slot l>>2 (+16), head hq.
        float denp = 0.f;
        for (int i = l >> 2; i < npad; i += 16) {
            int u = 0; float w = 0.f;
            if (i < rowlen) {
                u = colidx[s0 + i];
                float ev = es[((unsigned)u << 2) + hq] + edv;
                ev = fmaxf(ev, 0.2f * ev);   // leaky_relu, slope<1 => max form
                w = __expf(ev);              // no max-shift: softmax shift-invariant
            }
            denp += w;
            int bi = i * SLOTW + hq;
            wbase[bi] = w;
            wbase[bi + 4] = __uint_as_float((unsigned)u);
        }
#pragma unroll
        for (int off = 4; off <= 32; off <<= 1) denp += __shfl_xor(denp, off);
        den = denp;                          // full denom for head hq, every lane
        // ---- phase 2: MAC. half hf does slots {sp+hf, sp+hf+2, sp+hf+4, sp+hf+6}.
        for (int sp = 0; sp < npad; sp += 8) {
            int b0 = (sp + hf) * SLOTW + hq;
#pragma unroll
            for (int qq = 0; qq < 4; ++qq) {
                float w = wbase[b0 + qq * 2 * SLOTW];
                unsigned u = __float_as_uint(wbase[b0 + qq * 2 * SLOTW + 4]);
                uint2 xw = *(const uint2*)&xpk[(u << 6) + xsel];
                float2 x0 = unpack_bf16(xw.x);
                float2 x1 = unpack_bf16(xw.y);
                a0 = fmaf(w, x0.x, a0);
                a1 = fmaf(w, x0.y, a1);
                a2 = fmaf(w, x1.x, a2);
                a3 = fmaf(w, x1.y, a3);
            }
        }
        // combine even/odd halves (lanes l and l^32 own the same channels)
        a0 += __shfl_xor(a0, 32);
        a1 += __shfl_xor(a1, 32);
        a2 += __shfl_xor(a2, 32);
        a3 += __shfl_xor(a3, 32);
    } else {
        // ---- slow fallback (correctness insurance; not taken for this data)
        for (int e = s0; e < s1; ++e) {
            int u = colidx[e];
            float ev = es[((unsigned)u << 2) + hq] + edv;
            ev = fmaxf(ev, 0.2f * ev);
            float w = __expf(ev);
            den += w;
            uint2 xw = *(const uint2*)&xpk[((unsigned)u << 6) + xsel];
            float2 x0 = unpack_bf16(xw.x);
            float2 x1 = unpack_bf16(xw.y);
            a0 = fmaf(w, x0.x, a0);
            a1 = fmaf(w, x0.y, a1);
            a2 = fmaf(w, x1.x, a2);
            a3 = fmaf(w, x1.y, a3);
        }
        // halves computed all edges redundantly -> values already complete
    }
    float rd = 1.f / den;

    // ---- epilogue: residual + LN + relu on this lane's 4 channels.
    // Channel set is duplicated across halves -> reduce within 32-lane half only.
    float4 h4  = *(const float4*)&h[(size_t)v * 128 + c0];
    float4 bc4 = *(const float4*)&bc[c0];
    float y0 = a0 * rd + bc4.x + h4.x;
    float y1 = a1 * rd + bc4.y + h4.y;
    float y2 = a2 * rd + bc4.z + h4.z;
    float y3 = a3 * rd + bc4.w + h4.w;

    float s = y0 + y1 + y2 + y3;
#pragma unroll
    for (int off = 16; off >= 1; off >>= 1) s += __shfl_xor(s, off);
    float mean = s * (1.f / 128.f);
    float d0 = y0 - mean, d1 = y1 - mean, d2 = y2 - mean, d3 = y3 - mean;
    float vv = d0 * d0 + d1 * d1 + d2 * d2 + d3 * d3;
#pragma unroll
    for (int off = 16; off >= 1; off >>= 1) vv += __shfl_xor(vv, off);
    float rstd = rsqrtf(vv * (1.f / 128.f) + 1e-5f);
    float4 g4  = *(const float4*)&g[c0];
    float4 be4 = *(const float4*)&be[c0];
    float z0 = d0 * rstd * g4.x + be4.x;
    float z1 = d1 * rstd * g4.y + be4.y;
    float z2 = d2 * rstd * g4.z + be4.z;
    float z3 = d3 * rstd * g4.w + be4.w;
    if (hf == 0) {
        float4 o;
        o.x = z0 > 0.f ? z0 : 0.f;
        o.y = z1 > 0.f ? z1 : 0.f;
        o.z = z2 > 0.f ? z2 : 0.f;
        o.w = z3 > 0.f ? z3 : 0.f;
        *(float4*)&h[(size_t)v * 128 + c0] = o;
    }
}

extern "C" void kernel_launch(void* const* d_in, const int* in_sizes, int n_in,
                              void* d_out, int out_size, void* d_ws, size_t ws_size,
                              hipStream_t stream) {
    const float* x      = (const float*)d_in[0];
    const int*   ei     = (const int*)d_in[1];
    const float* enc_w1 = (const float*)d_in[2];
    const float* enc_b1 = (const float*)d_in[3];
    const float* enc_w2 = (const float*)d_in[4];
    const float* enc_b2 = (const float*)d_in[5];
    const float *W[3], *as_[3], *ad_[3], *bc[3], *g[3], *be[3];
    for (int l = 0; l < 3; ++l) {
        W[l]   = (const float*)d_in[6 + l * 6 + 0];
        as_[l] = (const float*)d_in[6 + l * 6 + 1];
        ad_[l] = (const float*)d_in[6 + l * 6 + 2];
        bc[l]  = (const float*)d_in[6 + l * 6 + 3];
        g[l]   = (const float*)d_in[6 + l * 6 + 4];
        be[l]  = (const float*)d_in[6 + l * 6 + 5];
    }
    const float* imp_w1 = (const float*)d_in[24];
    const float* imp_b1 = (const float*)d_in[25];
    const float* imp_w2 = (const float*)d_in[26];
    const float* imp_b2 = (const float*)d_in[27];
    const float* tim_w1 = (const float*)d_in[28];
    const float* tim_b1 = (const float*)d_in[29];
    const float* tim_w2 = (const float*)d_in[30];
    const float* tim_b2 = (const float*)d_in[31];

    int* gcursor = (int*)d_ws;               // NPART
    int* rowptr  = gcursor + NPART + 64;     // NN+1
    int* colidx  = rowptr + NN + 1;          // ETOT (+8 slack)
    uintptr_t pb = (uintptr_t)(colidx + ETOT + 8);
    pb = (pb + 255) & ~(uintptr_t)255;
    unsigned* pbuf = (unsigned*)pb;          // NPART*PCAP (7.3 MB)
    uintptr_t fb = (uintptr_t)(pbuf + (size_t)NPART * PCAP);
    fb = (fb + 255) & ~(uintptr_t)255;
    float* es = (float*)fb;                  // NN*4
    float* ed = es + (size_t)NN * 4;         // NN*4
    float* h  = ed + (size_t)NN * 4;         // NN*128 fp32
    float* xpf = h + (size_t)NN * 128;       // region sized NN*128 floats
    unsigned* xpk = (unsigned*)xpf;          // packed bf16 uses first half
    float* tmp = xpf;                        // enc1 scratch aliases (dead before xpk lives)

    hipMemsetAsync(gcursor, 0, NPART * sizeof(int), stream);
    pass1_kernel<<<512, 256, 0, stream>>>(ei, gcursor, pbuf);
    pass2_kernel<<<NPART, 256, 0, stream>>>(pbuf, gcursor, rowptr, colidx);

    const int GB64 = (NN + 63) / 64;
    gemm_small_kernel<128, true><<<(NN + 31) / 32, 256, 0, stream>>>(x, enc_w1, enc_b1, tmp, NN, FINDIM);
    gemm128_kernel<true, false><<<GB64, 256, 0, stream>>>(tmp, enc_w2, enc_b2, h, nullptr,
                                                          nullptr, nullptr, nullptr, nullptr, NN);

    for (int l = 0; l < 3; ++l) {
        gemm128_kernel<false, true><<<GB64, 256, 0, stream>>>(h, W[l], nullptr, nullptr, xpk,
                                                              as_[l], ad_[l], es, ed, NN);
        gat_kernel<<<(NN + 3) / 4, 256, 0, stream>>>(xpk, es, ed, rowptr, colidx, h,
                                                     bc[l], g[l], be[l]);
    }

    gemm_heads_kernel<<<GB64, 256, 0, stream>>>(h, imp_w1, imp_b1, tim_w1, tim_b1,
                                                imp_w2, imp_b2, tim_w2, tim_b2,
                                                (float*)d_out, NN);
}

// Round 3
// 595.605 us; speedup vs baseline: 1.1146x; 1.0233x over previous
//
#include <hip/hip_runtime.h>
#include <hip/hip_bf16.h>
#include <math.h>

#define NN 50000
#define EDGES 1600000
#define ETOT (EDGES + NN)
#define FINDIM 39
#define NPART 256
#define PSZ 196        // dsts per partition; 256*196 = 50176 >= NN
#define PCAP 7100      // capacity per partition (avg 6468, +7.9 sigma)
#define P1TILE 4096
#define MAXS 96        // fast-path max row len (avg 33, ~8sigma tail; fallback covers rest)
#define SLOTW 9        // dwords per LDS slot: w[4] at +hq, u(dup x4) at +4+hq, +1 pad

__device__ __forceinline__ unsigned pack_bf16(float a, float b) {
    __hip_bfloat162 t;
    t.x = __float2bfloat16(a);
    t.y = __float2bfloat16(b);
    return *(unsigned*)&t;
}
__device__ __forceinline__ float2 unpack_bf16(unsigned w) {
    float2 r;
    r.x = __uint_as_float(w << 16);
    r.y = __uint_as_float(w & 0xffff0000u);
    return r;
}

__device__ __forceinline__ int src_at(const int* ei, int i, bool i32) {
    return i32 ? ei[i] : ei[2 * i];
}
__device__ __forceinline__ int dst_at(const int* ei, int i, bool i32) {
    return i32 ? ei[EDGES + i] : ei[2 * (EDGES + i)];
}

// ---------------- CSR pass 1 (self-detecting int32/int64): bucket into 256 partitions ----------------
__global__ __launch_bounds__(256) void pass1_kernel(const int* __restrict__ ei,
                                                    int* __restrict__ gcursor,
                                                    unsigned* __restrict__ pbuf) {
    __shared__ unsigned raw[P1TILE];
    __shared__ unsigned srt[P1TILE];
    __shared__ int pcnt[NPART], poff[NPART], pcur[NPART], gb[NPART];
    __shared__ int i32flag;
    int t = threadIdx.x;
    if (t == 0) i32flag = 0;
    __syncthreads();
    int chunk = (ETOT + gridDim.x - 1) / gridDim.x;
    int c0 = blockIdx.x * chunk;
    int c1 = c0 + chunk; if (c1 > ETOT) c1 = ETOT;
    int sb = c0 < EDGES - 64 ? c0 : 0;
    if (t < 64 && ei[2 * (sb + t) + 1] != 0) i32flag = 1;
    __syncthreads();
    bool i32 = (i32flag != 0);
    for (int t0 = c0; t0 < c1; t0 += P1TILE) {
        int tn = c1 - t0; if (tn > P1TILE) tn = P1TILE;
        pcnt[t] = 0; pcur[t] = 0;
        __syncthreads();
        for (int i = t; i < tn; i += 256) {
            int e = t0 + i;
            int s, d;
            if (e < EDGES) { s = src_at(ei, e, i32); d = dst_at(ei, e, i32); }
            else { s = d = e - EDGES; }
            raw[i] = ((unsigned)s << 16) | (unsigned)d;
            atomicAdd(&pcnt[d / PSZ], 1);
        }
        __syncthreads();
        poff[t] = pcnt[t];
        __syncthreads();
        for (int off = 1; off < NPART; off <<= 1) {
            int v = (t >= off) ? poff[t - off] : 0;
            __syncthreads();
            poff[t] += v;
            __syncthreads();
        }
        poff[t] -= pcnt[t];                       // exclusive
        gb[t] = atomicAdd(&gcursor[t], pcnt[t]);  // global base for this tile's run
        __syncthreads();
        for (int i = t; i < tn; i += 256) {
            unsigned r = raw[i];
            int part = (int)(r & 0xFFFFu) / PSZ;
            int pos = poff[part] + atomicAdd(&pcur[part], 1);
            srt[pos] = r;
        }
        __syncthreads();
        for (int i = t; i < tn; i += 256) {
            unsigned r = srt[i];
            int part = (int)(r & 0xFFFFu) / PSZ;
            int gpos = gb[part] + (i - poff[part]);
            if (gpos < PCAP) pbuf[(size_t)part * PCAP + gpos] = r;
        }
        __syncthreads();
    }
}

// ---------------- CSR pass 2: per-partition exact sort -> rowptr + colidx (pbase inline) ----------------
__global__ __launch_bounds__(256) void pass2_kernel(const unsigned* __restrict__ pbuf,
                                                    const int* __restrict__ gcursor,
                                                    int* __restrict__ rowptr,
                                                    int* __restrict__ colidx) {
    __shared__ unsigned recs[PCAP];                 // 28.4 KB
    __shared__ int lhist[PSZ], lexcl[PSZ], lcur[PSZ];
    __shared__ int psm[NPART];
    int p = blockIdx.x;
    int t = threadIdx.x;
    // inline prefix over the 256 partition totals
    psm[t] = gcursor[t];
    __syncthreads();
    for (int off = 1; off < NPART; off <<= 1) {
        int x = (t >= off) ? psm[t - off] : 0;
        __syncthreads();
        psm[t] += x;
        __syncthreads();
    }
    int n = gcursor[p]; if (n > PCAP) n = PCAP;
    int base = psm[p] - gcursor[p];
    if (p == NPART - 1 && t == 0) rowptr[NN] = psm[NPART - 1];   // == ETOT
    int d0 = p * PSZ;
    int nd = NN - d0; if (nd > PSZ) nd = PSZ;
    if (nd < 0) nd = 0;
    for (int i = t; i < nd; i += 256) { lhist[i] = 0; lcur[i] = 0; }
    __syncthreads();
    for (int i = t; i < n; i += 256) {
        unsigned r = pbuf[(size_t)p * PCAP + i];
        recs[i] = r;
        atomicAdd(&lhist[(int)(r & 0xFFFFu) - d0], 1);
    }
    __syncthreads();
    for (int i = t; i < nd; i += 256) lexcl[i] = lhist[i];
    __syncthreads();
    for (int off = 1; off < PSZ; off <<= 1) {
        int a0 = 0;
        if (t < nd && t >= off) a0 = lexcl[t - off];
        __syncthreads();
        if (t < nd) lexcl[t] += a0;
        __syncthreads();
    }
    for (int i = t; i < nd; i += 256) {
        lexcl[i] -= lhist[i];                        // exclusive
        rowptr[d0 + i] = base + lexcl[i];
    }
    __syncthreads();
    for (int i = t; i < n; i += 256) {
        unsigned r = recs[i];
        int li = (int)(r & 0xFFFFu) - d0;
        int pos = base + lexcl[li] + atomicAdd(&lcur[li], 1);
        colidx[pos] = (int)(r >> 16);
    }
}

// ---------------- generic GEMM (K=39 encoder-1 only) ----------------
template <int NC, bool RELU>
__global__ __launch_bounds__(256) void gemm_small_kernel(const float* __restrict__ A,
                                                         const float* __restrict__ B,
                                                         const float* __restrict__ bias,
                                                         float* __restrict__ C, int M, int K) {
    constexpr int TM = 32;
    constexpr int GROUPS = 256 / NC;
    constexpr int RPG = TM / GROUPS;
    constexpr int KC = 64;
    __shared__ float As[TM * 128];
    __shared__ float Bs[KC * NC];
    int t = threadIdx.x;
    int i0 = blockIdx.x * TM;

    int rows = M - i0; if (rows > TM) rows = TM;
    for (int idx = t; idx < rows * K; idx += 256) {
        int r = idx / K, k = idx - r * K;
        As[r * K + k] = A[(size_t)(i0 + r) * K + k];
    }

    int col = t % NC, grp = t / NC;
    int rg0 = grp * RPG;
    float acc[RPG];
#pragma unroll
    for (int r = 0; r < RPG; ++r) acc[r] = 0.f;

    for (int k0 = 0; k0 < K; k0 += KC) {
        int kc = K - k0; if (kc > KC) kc = KC;
        __syncthreads();
        for (int idx = t; idx < kc * NC; idx += 256) Bs[idx] = B[(size_t)k0 * NC + idx];
        __syncthreads();
        for (int k = 0; k < kc; ++k) {
            float bv = Bs[k * NC + col];
#pragma unroll
            for (int r = 0; r < RPG; ++r) acc[r] += As[(rg0 + r) * K + k0 + k] * bv;
        }
    }

    float bb = bias ? bias[col] : 0.f;
#pragma unroll
    for (int r = 0; r < RPG; ++r) {
        int i = i0 + rg0 + r;
        if (i < M) {
            float v = acc[r] + bb;
            if (RELU) v = v > 0.f ? v : 0.f;
            C[(size_t)i * NC + col] = v;
        }
    }
}

// ---------------- fast GEMM 128x128, 24KB LDS; EPI: packed-bf16 xp + es/ed ----------------
template <bool BIAS, bool EPI>
__global__ __launch_bounds__(256) void gemm128_kernel(const float* __restrict__ A,
                                                      const float* __restrict__ B,
                                                      const float* __restrict__ bias,
                                                      float* __restrict__ C,
                                                      unsigned* __restrict__ XP,
                                                      const float* __restrict__ a_s,
                                                      const float* __restrict__ a_d,
                                                      float* __restrict__ es,
                                                      float* __restrict__ ed, int M) {
    __shared__ float As[64 * 32];    // 8 KB : 64 rows x 32-k chunk
    __shared__ float Bs[32 * 128];   // 16 KB: 32-k chunk x 128 cols
    int t = threadIdx.x;
    int i0 = blockIdx.x * 64;
    int tc = t & 31;                 // cols tc*4 .. tc*4+3
    int tr = t >> 5;
    int r0 = tr * 8;
    int c0 = tc * 4;

    float acc[8][4];
#pragma unroll
    for (int i = 0; i < 8; ++i)
#pragma unroll
        for (int j = 0; j < 4; ++j) acc[i][j] = 0.f;

    for (int k0 = 0; k0 < 128; k0 += 32) {
        __syncthreads();
#pragma unroll
        for (int q = 0; q < 2; ++q) {
            int idx = t + q * 256;           // 0..511
            int r = idx >> 3, kq = idx & 7;
            float4 v4 = make_float4(0.f, 0.f, 0.f, 0.f);
            if (i0 + r < M) v4 = *(const float4*)&A[(size_t)(i0 + r) * 128 + k0 + kq * 4];
            *(float4*)&As[r * 32 + kq * 4] = v4;
        }
#pragma unroll
        for (int q = 0; q < 4; ++q) {
            int idx = (t + q * 256) * 4;
            *(float4*)&Bs[idx] = *(const float4*)&B[(size_t)k0 * 128 + idx];
        }
        __syncthreads();
#pragma unroll 8
        for (int k = 0; k < 32; k += 4) {
            float4 a4[8];
#pragma unroll
            for (int i = 0; i < 8; ++i)
                a4[i] = *(const float4*)&As[(r0 + i) * 32 + k];
            float4 b4[4];
#pragma unroll
            for (int kk = 0; kk < 4; ++kk)
                b4[kk] = *(const float4*)&Bs[(k + kk) * 128 + c0];
#pragma unroll
            for (int i = 0; i < 8; ++i) {
                const float* av = (const float*)&a4[i];
#pragma unroll
                for (int kk = 0; kk < 4; ++kk) {
                    acc[i][0] += av[kk] * b4[kk].x;
                    acc[i][1] += av[kk] * b4[kk].y;
                    acc[i][2] += av[kk] * b4[kk].z;
                    acc[i][3] += av[kk] * b4[kk].w;
                }
            }
        }
    }

    if (!EPI) {
        float4 bias4 = make_float4(0.f, 0.f, 0.f, 0.f);
        if (BIAS) bias4 = *(const float4*)&bias[c0];
#pragma unroll
        for (int i = 0; i < 8; ++i) {
            int row = i0 + r0 + i;
            if (row < M) {
                float4 o;
                o.x = acc[i][0] + bias4.x;
                o.y = acc[i][1] + bias4.y;
                o.z = acc[i][2] + bias4.z;
                o.w = acc[i][3] + bias4.w;
                *(float4*)&C[(size_t)row * 128 + c0] = o;
            }
        }
    } else {
#pragma unroll
        for (int i = 0; i < 8; ++i) {
            int row = i0 + r0 + i;
            if (row < M) {
                uint2 o;
                o.x = pack_bf16(acc[i][0], acc[i][1]);
                o.y = pack_bf16(acc[i][2], acc[i][3]);
                *(uint2*)&XP[(size_t)row * 64 + tc * 2] = o;
            }
        }
        int hd = tc >> 3;
        float4 s4 = *(const float4*)&a_s[c0];
        float4 d4 = *(const float4*)&a_d[c0];
#pragma unroll
        for (int i = 0; i < 8; ++i) {
            int row = i0 + r0 + i;
            float s = acc[i][0] * s4.x + acc[i][1] * s4.y + acc[i][2] * s4.z + acc[i][3] * s4.w;
            float d = acc[i][0] * d4.x + acc[i][1] * d4.y + acc[i][2] * d4.z + acc[i][3] * d4.w;
#pragma unroll
            for (int off = 4; off >= 1; off >>= 1) {
                s += __shfl_xor(s, off);
                d += __shfl_xor(d, off);
            }
            if ((tc & 7) == 0 && row < M) {
                es[row * 4 + hd] = s;
                ed[row * 4 + hd] = d;
            }
        }
    }
}

// ---------------- head GEMMs fully fused: h -> out (impact+timing), 24KB LDS ----------------
__global__ __launch_bounds__(256) void gemm_heads_kernel(const float* __restrict__ A,
                                                         const float* __restrict__ iw1,
                                                         const float* __restrict__ ib1,
                                                         const float* __restrict__ tw1,
                                                         const float* __restrict__ tb1,
                                                         const float* __restrict__ iw2,
                                                         const float* __restrict__ ib2,
                                                         const float* __restrict__ tw2,
                                                         const float* __restrict__ tb2,
                                                         float* __restrict__ out, int M) {
    __shared__ float As[64 * 32];
    __shared__ float Bs[32 * 128];
    int t = threadIdx.x;
    int i0 = blockIdx.x * 64;
    int tc = t & 31;
    int tr = t >> 5;
    int r0 = tr * 8;
    int c0 = tc * 4;                 // virtual col (0-63 impact, 64-127 timing)

    float acc[8][4];
#pragma unroll
    for (int i = 0; i < 8; ++i)
#pragma unroll
        for (int j = 0; j < 4; ++j) acc[i][j] = 0.f;

    for (int k0 = 0; k0 < 128; k0 += 32) {
        __syncthreads();
#pragma unroll
        for (int q = 0; q < 2; ++q) {
            int idx = t + q * 256;
            int r = idx >> 3, kq = idx & 7;
            float4 v4 = make_float4(0.f, 0.f, 0.f, 0.f);
            if (i0 + r < M) v4 = *(const float4*)&A[(size_t)(i0 + r) * 128 + k0 + kq * 4];
            *(float4*)&As[r * 32 + kq * 4] = v4;
        }
#pragma unroll
        for (int q = 0; q < 4; ++q) {
            int idx = (t + q * 256) * 4;       // flat into [32][128]
            int k = idx >> 7, cl = idx & 127;
            float4 v4 = (cl < 64)
                ? *(const float4*)&iw1[(size_t)(k0 + k) * 64 + cl]
                : *(const float4*)&tw1[(size_t)(k0 + k) * 64 + (cl - 64)];
            *(float4*)&Bs[idx] = v4;
        }
        __syncthreads();
#pragma unroll 8
        for (int k = 0; k < 32; k += 4) {
            float4 a4[8];
#pragma unroll
            for (int i = 0; i < 8; ++i)
                a4[i] = *(const float4*)&As[(r0 + i) * 32 + k];
            float4 b4[4];
#pragma unroll
            for (int kk = 0; kk < 4; ++kk)
                b4[kk] = *(const float4*)&Bs[(k + kk) * 128 + c0];
#pragma unroll
            for (int i = 0; i < 8; ++i) {
                const float* av = (const float*)&a4[i];
#pragma unroll
                for (int kk = 0; kk < 4; ++kk) {
                    acc[i][0] += av[kk] * b4[kk].x;
                    acc[i][1] += av[kk] * b4[kk].y;
                    acc[i][2] += av[kk] * b4[kk].z;
                    acc[i][3] += av[kk] * b4[kk].w;
                }
            }
        }
    }

    bool isimp = (tc < 16);
    int lc = isimp ? c0 : (c0 - 64);
    float v[8][4];
#pragma unroll
    for (int i = 0; i < 8; ++i)
#pragma unroll
        for (int j = 0; j < 4; ++j) {
            float b = isimp ? ib1[lc + j] : tb1[lc + j];
            float x = acc[i][j] + b;
            v[i][j] = x > 0.f ? x : 0.f;
        }
#pragma unroll
    for (int i = 0; i < 8; ++i) {
        int row = i0 + r0 + i;
        if (isimp) {
#pragma unroll
            for (int c = 0; c < 3; ++c) {
                float pc = v[i][0] * iw2[(lc + 0) * 3 + c] + v[i][1] * iw2[(lc + 1) * 3 + c]
                         + v[i][2] * iw2[(lc + 2) * 3 + c] + v[i][3] * iw2[(lc + 3) * 3 + c];
#pragma unroll
                for (int off = 8; off >= 1; off >>= 1) pc += __shfl_xor(pc, off);
                if (tc == 0 && row < M) out[(size_t)row * 3 + c] = pc + ib2[c];
            }
        } else {
#pragma unroll
            for (int d = 0; d < 2; ++d) {
                float pd = v[i][0] * tw2[(lc + 0) * 2 + d] + v[i][1] * tw2[(lc + 1) * 2 + d]
                         + v[i][2] * tw2[(lc + 2) * 2 + d] + v[i][3] * tw2[(lc + 3) * 2 + d];
#pragma unroll
                for (int off = 8; off >= 1; off >>= 1) pd += __shfl_xor(pd, off);
                if (tc == 16 && row < M) {
                    float a = pd + tb2[d];
                    float sp = a > 20.f ? a : log1pf(__expf(a));
                    out[(size_t)(NN * 3) + (size_t)row * 2 + d] = sp;
                }
            }
        }
    }
}

// ---------------- gat v9: two-phase + explicit software pipelining.
// Phase 1: fixed unroll-6 (MAXS=96): all colidx loads in flight, then all es
// gathers in flight, then exps -> per-wave LDS table {w[4], u x4} per slot.
// Phase 2: double-buffered MAC: issue next iter's LDS reads + 4 gathers BEFORE
// consuming current iter's registers -> 4 gathers continuously in flight per wave
// (v8 kept them in flight only ~15% of the time -> latency-bound at 33% VALU).
// h-row float4 load hoisted to kernel top (off the epilogue critical path).
__global__ __launch_bounds__(256) void gat_kernel(const unsigned* __restrict__ xpk,
                                                  const float* __restrict__ es,
                                                  const float* __restrict__ ed,
                                                  const int* __restrict__ rowptr,
                                                  const int* __restrict__ colidx,
                                                  float* __restrict__ h,   // in-out (residual)
                                                  const float* __restrict__ bc,
                                                  const float* __restrict__ g,
                                                  const float* __restrict__ be) {
    __shared__ float wl[4][MAXS * SLOTW];   // 4 waves x 3.375 KB = 13.5 KB
    int wv = threadIdx.x >> 6, l = threadIdx.x & 63;
    int v = blockIdx.x * 4 + wv;
    if (v >= NN) return;
    int s0 = rowptr[v], s1 = rowptr[v + 1];
    int rowlen = s1 - s0;
    int hq = l & 3;                         // head (same in both phases & epilogue)
    int hf = l >> 5;                        // wave half: even/odd edge slots
    int j2 = (l & 31) >> 2;                 // 0..7 within-head quad index
    int c0 = (hq << 5) + (j2 << 2);         // 4 channels owned by this lane
    int xsel = (hq << 4) + (j2 << 1);       // even dword index into 64-dword xpk row
    float edv = ed[((unsigned)v << 2) + hq];
    float* wbase = wl[wv];

    // hoisted: residual row load overlaps both phases
    float4 h4 = *(const float4*)&h[(size_t)v * 128 + c0];

    float a0 = 0.f, a1 = 0.f, a2 = 0.f, a3 = 0.f;
    float den = 0.f;

    if (rowlen <= MAXS) {
        int npad = (rowlen + 7) & ~7;
        int sl = l >> 2;                    // slot this lane serves in phase 1
        // ---- phase 1: weights, fully unrolled with batched independent loads
        unsigned uu[6];
        float wk[6];
#pragma unroll
        for (int k = 0; k < 6; ++k) {
            int i = sl + 16 * k;
            uu[k] = (i < rowlen) ? (unsigned)colidx[s0 + i] : 0u;
        }
#pragma unroll
        for (int k = 0; k < 6; ++k) {
            int i = sl + 16 * k;
            float w = 0.f;
            if (i < rowlen) {
                float ev = es[(uu[k] << 2) + hq] + edv;
                ev = fmaxf(ev, 0.2f * ev);   // leaky_relu, slope<1 => max form
                w = __expf(ev);              // no max-shift: softmax shift-invariant
            }
            wk[k] = w;
        }
        float denp = 0.f;
#pragma unroll
        for (int k = 0; k < 6; ++k) {
            int i = sl + 16 * k;
            denp += wk[k];
            if (i < npad) {
                int bi = i * SLOTW + hq;
                wbase[bi] = wk[k];
                wbase[bi + 4] = __uint_as_float(uu[k]);
            }
        }
#pragma unroll
        for (int off = 4; off <= 32; off <<= 1) denp += __shfl_xor(denp, off);
        den = denp;                          // full denom for head hq, every lane
        // ---- phase 2: double-buffered MAC. half hf does slots {sp+hf+2q}.
        float wcur[4]; uint2 xcur[4];
        {
            int b0 = hf * SLOTW + hq;
            unsigned ucur[4];
#pragma unroll
            for (int qq = 0; qq < 4; ++qq) {
                int bi = b0 + qq * 2 * SLOTW;
                wcur[qq] = wbase[bi];
                ucur[qq] = __float_as_uint(wbase[bi + 4]);
            }
#pragma unroll
            for (int qq = 0; qq < 4; ++qq)
                xcur[qq] = *(const uint2*)&xpk[(ucur[qq] << 6) + xsel];
        }
        for (int sp = 8; sp < npad; sp += 8) {
            float wn[4]; unsigned un[4]; uint2 xn[4];
#pragma unroll
            for (int qq = 0; qq < 4; ++qq) {
                int bi = (sp + hf + 2 * qq) * SLOTW + hq;
                wn[qq] = wbase[bi];
                un[qq] = __float_as_uint(wbase[bi + 4]);
            }
#pragma unroll
            for (int qq = 0; qq < 4; ++qq)
                xn[qq] = *(const uint2*)&xpk[(un[qq] << 6) + xsel];
            // consume previous iteration while new gathers are in flight
#pragma unroll
            for (int qq = 0; qq < 4; ++qq) {
                float2 x0 = unpack_bf16(xcur[qq].x);
                float2 x1 = unpack_bf16(xcur[qq].y);
                a0 = fmaf(wcur[qq], x0.x, a0);
                a1 = fmaf(wcur[qq], x0.y, a1);
                a2 = fmaf(wcur[qq], x1.x, a2);
                a3 = fmaf(wcur[qq], x1.y, a3);
            }
#pragma unroll
            for (int qq = 0; qq < 4; ++qq) { wcur[qq] = wn[qq]; xcur[qq] = xn[qq]; }
        }
#pragma unroll
        for (int qq = 0; qq < 4; ++qq) {
            float2 x0 = unpack_bf16(xcur[qq].x);
            float2 x1 = unpack_bf16(xcur[qq].y);
            a0 = fmaf(wcur[qq], x0.x, a0);
            a1 = fmaf(wcur[qq], x0.y, a1);
            a2 = fmaf(wcur[qq], x1.x, a2);
            a3 = fmaf(wcur[qq], x1.y, a3);
        }
        // combine even/odd halves (lanes l and l^32 own the same channels)
        a0 += __shfl_xor(a0, 32);
        a1 += __shfl_xor(a1, 32);
        a2 += __shfl_xor(a2, 32);
        a3 += __shfl_xor(a3, 32);
    } else {
        // ---- slow fallback (correctness insurance; not taken for this data)
        for (int e = s0; e < s1; ++e) {
            int u = colidx[e];
            float ev = es[((unsigned)u << 2) + hq] + edv;
            ev = fmaxf(ev, 0.2f * ev);
            float w = __expf(ev);
            den += w;
            uint2 xw = *(const uint2*)&xpk[((unsigned)u << 6) + xsel];
            float2 x0 = unpack_bf16(xw.x);
            float2 x1 = unpack_bf16(xw.y);
            a0 = fmaf(w, x0.x, a0);
            a1 = fmaf(w, x0.y, a1);
            a2 = fmaf(w, x1.x, a2);
            a3 = fmaf(w, x1.y, a3);
        }
        // halves computed all edges redundantly -> values already complete
    }
    float rd = 1.f / den;

    // ---- epilogue: residual + LN + relu on this lane's 4 channels.
    float4 bc4 = *(const float4*)&bc[c0];
    float y0 = a0 * rd + bc4.x + h4.x;
    float y1 = a1 * rd + bc4.y + h4.y;
    float y2 = a2 * rd + bc4.z + h4.z;
    float y3 = a3 * rd + bc4.w + h4.w;

    float s = y0 + y1 + y2 + y3;
#pragma unroll
    for (int off = 16; off >= 1; off >>= 1) s += __shfl_xor(s, off);
    float mean = s * (1.f / 128.f);
    float d0 = y0 - mean, d1 = y1 - mean, d2 = y2 - mean, d3 = y3 - mean;
    float vv = d0 * d0 + d1 * d1 + d2 * d2 + d3 * d3;
#pragma unroll
    for (int off = 16; off >= 1; off >>= 1) vv += __shfl_xor(vv, off);
    float rstd = rsqrtf(vv * (1.f / 128.f) + 1e-5f);
    float4 g4  = *(const float4*)&g[c0];
    float4 be4 = *(const float4*)&be[c0];
    float z0 = d0 * rstd * g4.x + be4.x;
    float z1 = d1 * rstd * g4.y + be4.y;
    float z2 = d2 * rstd * g4.z + be4.z;
    float z3 = d3 * rstd * g4.w + be4.w;
    if (hf == 0) {
        float4 o;
        o.x = z0 > 0.f ? z0 : 0.f;
        o.y = z1 > 0.f ? z1 : 0.f;
        o.z = z2 > 0.f ? z2 : 0.f;
        o.w = z3 > 0.f ? z3 : 0.f;
        *(float4*)&h[(size_t)v * 128 + c0] = o;
    }
}

extern "C" void kernel_launch(void* const* d_in, const int* in_sizes, int n_in,
                              void* d_out, int out_size, void* d_ws, size_t ws_size,
                              hipStream_t stream) {
    const float* x      = (const float*)d_in[0];
    const int*   ei     = (const int*)d_in[1];
    const float* enc_w1 = (const float*)d_in[2];
    const float* enc_b1 = (const float*)d_in[3];
    const float* enc_w2 = (const float*)d_in[4];
    const float* enc_b2 = (const float*)d_in[5];
    const float *W[3], *as_[3], *ad_[3], *bc[3], *g[3], *be[3];
    for (int l = 0; l < 3; ++l) {
        W[l]   = (const float*)d_in[6 + l * 6 + 0];
        as_[l] = (const float*)d_in[6 + l * 6 + 1];
        ad_[l] = (const float*)d_in[6 + l * 6 + 2];
        bc[l]  = (const float*)d_in[6 + l * 6 + 3];
        g[l]   = (const float*)d_in[6 + l * 6 + 4];
        be[l]  = (const float*)d_in[6 + l * 6 + 5];
    }
    const float* imp_w1 = (const float*)d_in[24];
    const float* imp_b1 = (const float*)d_in[25];
    const float* imp_w2 = (const float*)d_in[26];
    const float* imp_b2 = (const float*)d_in[27];
    const float* tim_w1 = (const float*)d_in[28];
    const float* tim_b1 = (const float*)d_in[29];
    const float* tim_w2 = (const float*)d_in[30];
    const float* tim_b2 = (const float*)d_in[31];

    int* gcursor = (int*)d_ws;               // NPART
    int* rowptr  = gcursor + NPART + 64;     // NN+1
    int* colidx  = rowptr + NN + 1;          // ETOT (+8 slack)
    uintptr_t pb = (uintptr_t)(colidx + ETOT + 8);
    pb = (pb + 255) & ~(uintptr_t)255;
    unsigned* pbuf = (unsigned*)pb;          // NPART*PCAP (7.3 MB)
    uintptr_t fb = (uintptr_t)(pbuf + (size_t)NPART * PCAP);
    fb = (fb + 255) & ~(uintptr_t)255;
    float* es = (float*)fb;                  // NN*4
    float* ed = es + (size_t)NN * 4;         // NN*4
    float* h  = ed + (size_t)NN * 4;         // NN*128 fp32
    float* xpf = h + (size_t)NN * 128;       // region sized NN*128 floats
    unsigned* xpk = (unsigned*)xpf;          // packed bf16 uses first half
    float* tmp = xpf;                        // enc1 scratch aliases (dead before xpk lives)

    hipMemsetAsync(gcursor, 0, NPART * sizeof(int), stream);
    pass1_kernel<<<512, 256, 0, stream>>>(ei, gcursor, pbuf);
    pass2_kernel<<<NPART, 256, 0, stream>>>(pbuf, gcursor, rowptr, colidx);

    const int GB64 = (NN + 63) / 64;
    gemm_small_kernel<128, true><<<(NN + 31) / 32, 256, 0, stream>>>(x, enc_w1, enc_b1, tmp, NN, FINDIM);
    gemm128_kernel<true, false><<<GB64, 256, 0, stream>>>(tmp, enc_w2, enc_b2, h, nullptr,
                                                          nullptr, nullptr, nullptr, nullptr, NN);

    for (int l = 0; l < 3; ++l) {
        gemm128_kernel<false, true><<<GB64, 256, 0, stream>>>(h, W[l], nullptr, nullptr, xpk,
                                                              as_[l], ad_[l], es, ed, NN);
        gat_kernel<<<(NN + 3) / 4, 256, 0, stream>>>(xpk, es, ed, rowptr, colidx, h,
                                                     bc[l], g[l], be[l]);
    }

    gemm_heads_kernel<<<GB64, 256, 0, stream>>>(h, imp_w1, imp_b1, tim_w1, tim_b1,
                                                imp_w2, imp_b2, tim_w2, tim_b2,
                                                (float*)d_out, NN);
}

// Round 5
// 562.473 us; speedup vs baseline: 1.1802x; 1.0589x over previous
//
#include <hip/hip_runtime.h>
#include <hip/hip_bf16.h>
#include <math.h>

#define NN 50000
#define EDGES 1600000
#define ETOT (EDGES + NN)
#define FINDIM 39
#define NPART 256
#define PSZ 196        // dsts per partition; 256*196 = 50176 >= NN
#define PCAP 7100      // capacity per partition (avg 6468, +7.9 sigma)
#define P1TILE 4096

__device__ __forceinline__ unsigned pack_bf16(float a, float b) {
    __hip_bfloat162 t;
    t.x = __float2bfloat16(a);
    t.y = __float2bfloat16(b);
    return *(unsigned*)&t;
}
__device__ __forceinline__ float2 unpack_bf16(unsigned w) {
    float2 r;
    r.x = __uint_as_float(w << 16);
    r.y = __uint_as_float(w & 0xffff0000u);
    return r;
}

__device__ __forceinline__ int src_at(const int* ei, int i, bool i32) {
    return i32 ? ei[i] : ei[2 * i];
}
__device__ __forceinline__ int dst_at(const int* ei, int i, bool i32) {
    return i32 ? ei[EDGES + i] : ei[2 * (EDGES + i)];
}

// ---------------- CSR pass 1 (self-detecting int32/int64): bucket into 256 partitions ----------------
__global__ __launch_bounds__(256) void pass1_kernel(const int* __restrict__ ei,
                                                    int* __restrict__ gcursor,
                                                    unsigned* __restrict__ pbuf) {
    __shared__ unsigned raw[P1TILE];
    __shared__ unsigned srt[P1TILE];
    __shared__ int pcnt[NPART], poff[NPART], pcur[NPART], gb[NPART];
    __shared__ int i32flag;
    int t = threadIdx.x;
    if (t == 0) i32flag = 0;
    __syncthreads();
    int chunk = (ETOT + gridDim.x - 1) / gridDim.x;
    int c0 = blockIdx.x * chunk;
    int c1 = c0 + chunk; if (c1 > ETOT) c1 = ETOT;
    int sb = c0 < EDGES - 64 ? c0 : 0;
    if (t < 64 && ei[2 * (sb + t) + 1] != 0) i32flag = 1;
    __syncthreads();
    bool i32 = (i32flag != 0);
    for (int t0 = c0; t0 < c1; t0 += P1TILE) {
        int tn = c1 - t0; if (tn > P1TILE) tn = P1TILE;
        pcnt[t] = 0; pcur[t] = 0;
        __syncthreads();
        for (int i = t; i < tn; i += 256) {
            int e = t0 + i;
            int s, d;
            if (e < EDGES) { s = src_at(ei, e, i32); d = dst_at(ei, e, i32); }
            else { s = d = e - EDGES; }
            raw[i] = ((unsigned)s << 16) | (unsigned)d;
            atomicAdd(&pcnt[d / PSZ], 1);
        }
        __syncthreads();
        poff[t] = pcnt[t];
        __syncthreads();
        for (int off = 1; off < NPART; off <<= 1) {
            int v = (t >= off) ? poff[t - off] : 0;
            __syncthreads();
            poff[t] += v;
            __syncthreads();
        }
        poff[t] -= pcnt[t];                       // exclusive
        gb[t] = atomicAdd(&gcursor[t], pcnt[t]);  // global base for this tile's run
        __syncthreads();
        for (int i = t; i < tn; i += 256) {
            unsigned r = raw[i];
            int part = (int)(r & 0xFFFFu) / PSZ;
            int pos = poff[part] + atomicAdd(&pcur[part], 1);
            srt[pos] = r;
        }
        __syncthreads();
        for (int i = t; i < tn; i += 256) {
            unsigned r = srt[i];
            int part = (int)(r & 0xFFFFu) / PSZ;
            int gpos = gb[part] + (i - poff[part]);
            if (gpos < PCAP) pbuf[(size_t)part * PCAP + gpos] = r;
        }
        __syncthreads();
    }
}

// ---------------- CSR pass 2: per-partition exact sort -> rowptr + colidx (pbase inline) ----------------
__global__ __launch_bounds__(256) void pass2_kernel(const unsigned* __restrict__ pbuf,
                                                    const int* __restrict__ gcursor,
                                                    int* __restrict__ rowptr,
                                                    int* __restrict__ colidx) {
    __shared__ unsigned recs[PCAP];                 // 28.4 KB
    __shared__ int lhist[PSZ], lexcl[PSZ], lcur[PSZ];
    __shared__ int psm[NPART];
    int p = blockIdx.x;
    int t = threadIdx.x;
    // inline prefix over the 256 partition totals
    psm[t] = gcursor[t];
    __syncthreads();
    for (int off = 1; off < NPART; off <<= 1) {
        int x = (t >= off) ? psm[t - off] : 0;
        __syncthreads();
        psm[t] += x;
        __syncthreads();
    }
    int n = gcursor[p]; if (n > PCAP) n = PCAP;
    int base = psm[p] - gcursor[p];
    if (p == NPART - 1 && t == 0) rowptr[NN] = psm[NPART - 1];   // == ETOT
    int d0 = p * PSZ;
    int nd = NN - d0; if (nd > PSZ) nd = PSZ;
    if (nd < 0) nd = 0;
    for (int i = t; i < nd; i += 256) { lhist[i] = 0; lcur[i] = 0; }
    __syncthreads();
    for (int i = t; i < n; i += 256) {
        unsigned r = pbuf[(size_t)p * PCAP + i];
        recs[i] = r;
        atomicAdd(&lhist[(int)(r & 0xFFFFu) - d0], 1);
    }
    __syncthreads();
    for (int i = t; i < nd; i += 256) lexcl[i] = lhist[i];
    __syncthreads();
    for (int off = 1; off < PSZ; off <<= 1) {
        int a0 = 0;
        if (t < nd && t >= off) a0 = lexcl[t - off];
        __syncthreads();
        if (t < nd) lexcl[t] += a0;
        __syncthreads();
    }
    for (int i = t; i < nd; i += 256) {
        lexcl[i] -= lhist[i];                        // exclusive
        rowptr[d0 + i] = base + lexcl[i];
    }
    __syncthreads();
    for (int i = t; i < n; i += 256) {
        unsigned r = recs[i];
        int li = (int)(r & 0xFFFFu) - d0;
        int pos = base + lexcl[li] + atomicAdd(&lcur[li], 1);
        colidx[pos] = (int)(r >> 16);
    }
}

// ---------------- generic GEMM (K=39 encoder-1 only) ----------------
template <int NC, bool RELU>
__global__ __launch_bounds__(256) void gemm_small_kernel(const float* __restrict__ A,
                                                         const float* __restrict__ B,
                                                         const float* __restrict__ bias,
                                                         float* __restrict__ C, int M, int K) {
    constexpr int TM = 32;
    constexpr int GROUPS = 256 / NC;
    constexpr int RPG = TM / GROUPS;
    constexpr int KC = 64;
    __shared__ float As[TM * 128];
    __shared__ float Bs[KC * NC];
    int t = threadIdx.x;
    int i0 = blockIdx.x * TM;

    int rows = M - i0; if (rows > TM) rows = TM;
    for (int idx = t; idx < rows * K; idx += 256) {
        int r = idx / K, k = idx - r * K;
        As[r * K + k] = A[(size_t)(i0 + r) * K + k];
    }

    int col = t % NC, grp = t / NC;
    int rg0 = grp * RPG;
    float acc[RPG];
#pragma unroll
    for (int r = 0; r < RPG; ++r) acc[r] = 0.f;

    for (int k0 = 0; k0 < K; k0 += KC) {
        int kc = K - k0; if (kc > KC) kc = KC;
        __syncthreads();
        for (int idx = t; idx < kc * NC; idx += 256) Bs[idx] = B[(size_t)k0 * NC + idx];
        __syncthreads();
        for (int k = 0; k < kc; ++k) {
            float bv = Bs[k * NC + col];
#pragma unroll
            for (int r = 0; r < RPG; ++r) acc[r] += As[(rg0 + r) * K + k0 + k] * bv;
        }
    }

    float bb = bias ? bias[col] : 0.f;
#pragma unroll
    for (int r = 0; r < RPG; ++r) {
        int i = i0 + rg0 + r;
        if (i < M) {
            float v = acc[r] + bb;
            if (RELU) v = v > 0.f ? v : 0.f;
            C[(size_t)i * NC + col] = v;
        }
    }
}

// ---------------- fast GEMM 128x128, 24KB LDS; EPI: packed-bf16 xp + es/ed ----------------
template <bool BIAS, bool EPI>
__global__ __launch_bounds__(256) void gemm128_kernel(const float* __restrict__ A,
                                                      const float* __restrict__ B,
                                                      const float* __restrict__ bias,
                                                      float* __restrict__ C,
                                                      unsigned* __restrict__ XP,
                                                      const float* __restrict__ a_s,
                                                      const float* __restrict__ a_d,
                                                      float* __restrict__ es,
                                                      float* __restrict__ ed, int M) {
    __shared__ float As[64 * 32];    // 8 KB : 64 rows x 32-k chunk
    __shared__ float Bs[32 * 128];   // 16 KB: 32-k chunk x 128 cols
    int t = threadIdx.x;
    int i0 = blockIdx.x * 64;
    int tc = t & 31;                 // cols tc*4 .. tc*4+3
    int tr = t >> 5;
    int r0 = tr * 8;
    int c0 = tc * 4;

    float acc[8][4];
#pragma unroll
    for (int i = 0; i < 8; ++i)
#pragma unroll
        for (int j = 0; j < 4; ++j) acc[i][j] = 0.f;

    for (int k0 = 0; k0 < 128; k0 += 32) {
        __syncthreads();
#pragma unroll
        for (int q = 0; q < 2; ++q) {
            int idx = t + q * 256;           // 0..511
            int r = idx >> 3, kq = idx & 7;
            float4 v4 = make_float4(0.f, 0.f, 0.f, 0.f);
            if (i0 + r < M) v4 = *(const float4*)&A[(size_t)(i0 + r) * 128 + k0 + kq * 4];
            *(float4*)&As[r * 32 + kq * 4] = v4;
        }
#pragma unroll
        for (int q = 0; q < 4; ++q) {
            int idx = (t + q * 256) * 4;
            *(float4*)&Bs[idx] = *(const float4*)&B[(size_t)k0 * 128 + idx];
        }
        __syncthreads();
#pragma unroll 8
        for (int k = 0; k < 32; k += 4) {
            float4 a4[8];
#pragma unroll
            for (int i = 0; i < 8; ++i)
                a4[i] = *(const float4*)&As[(r0 + i) * 32 + k];
            float4 b4[4];
#pragma unroll
            for (int kk = 0; kk < 4; ++kk)
                b4[kk] = *(const float4*)&Bs[(k + kk) * 128 + c0];
#pragma unroll
            for (int i = 0; i < 8; ++i) {
                const float* av = (const float*)&a4[i];
#pragma unroll
                for (int kk = 0; kk < 4; ++kk) {
                    acc[i][0] += av[kk] * b4[kk].x;
                    acc[i][1] += av[kk] * b4[kk].y;
                    acc[i][2] += av[kk] * b4[kk].z;
                    acc[i][3] += av[kk] * b4[kk].w;
                }
            }
        }
    }

    if (!EPI) {
        float4 bias4 = make_float4(0.f, 0.f, 0.f, 0.f);
        if (BIAS) bias4 = *(const float4*)&bias[c0];
#pragma unroll
        for (int i = 0; i < 8; ++i) {
            int row = i0 + r0 + i;
            if (row < M) {
                float4 o;
                o.x = acc[i][0] + bias4.x;
                o.y = acc[i][1] + bias4.y;
                o.z = acc[i][2] + bias4.z;
                o.w = acc[i][3] + bias4.w;
                *(float4*)&C[(size_t)row * 128 + c0] = o;
            }
        }
    } else {
#pragma unroll
        for (int i = 0; i < 8; ++i) {
            int row = i0 + r0 + i;
            if (row < M) {
                uint2 o;
                o.x = pack_bf16(acc[i][0], acc[i][1]);
                o.y = pack_bf16(acc[i][2], acc[i][3]);
                *(uint2*)&XP[(size_t)row * 64 + tc * 2] = o;
            }
        }
        int hd = tc >> 3;
        float4 s4 = *(const float4*)&a_s[c0];
        float4 d4 = *(const float4*)&a_d[c0];
#pragma unroll
        for (int i = 0; i < 8; ++i) {
            int row = i0 + r0 + i;
            float s = acc[i][0] * s4.x + acc[i][1] * s4.y + acc[i][2] * s4.z + acc[i][3] * s4.w;
            float d = acc[i][0] * d4.x + acc[i][1] * d4.y + acc[i][2] * d4.z + acc[i][3] * d4.w;
#pragma unroll
            for (int off = 4; off >= 1; off >>= 1) {
                s += __shfl_xor(s, off);
                d += __shfl_xor(d, off);
            }
            if ((tc & 7) == 0 && row < M) {
                es[row * 4 + hd] = s;
                ed[row * 4 + hd] = d;
            }
        }
    }
}

// ---------------- head GEMMs fully fused: h -> out (impact+timing), 24KB LDS ----------------
__global__ __launch_bounds__(256) void gemm_heads_kernel(const float* __restrict__ A,
                                                         const float* __restrict__ iw1,
                                                         const float* __restrict__ ib1,
                                                         const float* __restrict__ tw1,
                                                         const float* __restrict__ tb1,
                                                         const float* __restrict__ iw2,
                                                         const float* __restrict__ ib2,
                                                         const float* __restrict__ tw2,
                                                         const float* __restrict__ tb2,
                                                         float* __restrict__ out, int M) {
    __shared__ float As[64 * 32];
    __shared__ float Bs[32 * 128];
    int t = threadIdx.x;
    int i0 = blockIdx.x * 64;
    int tc = t & 31;
    int tr = t >> 5;
    int r0 = tr * 8;
    int c0 = tc * 4;                 // virtual col (0-63 impact, 64-127 timing)

    float acc[8][4];
#pragma unroll
    for (int i = 0; i < 8; ++i)
#pragma unroll
        for (int j = 0; j < 4; ++j) acc[i][j] = 0.f;

    for (int k0 = 0; k0 < 128; k0 += 32) {
        __syncthreads();
#pragma unroll
        for (int q = 0; q < 2; ++q) {
            int idx = t + q * 256;
            int r = idx >> 3, kq = idx & 7;
            float4 v4 = make_float4(0.f, 0.f, 0.f, 0.f);
            if (i0 + r < M) v4 = *(const float4*)&A[(size_t)(i0 + r) * 128 + k0 + kq * 4];
            *(float4*)&As[r * 32 + kq * 4] = v4;
        }
#pragma unroll
        for (int q = 0; q < 4; ++q) {
            int idx = (t + q * 256) * 4;       // flat into [32][128]
            int k = idx >> 7, cl = idx & 127;
            float4 v4 = (cl < 64)
                ? *(const float4*)&iw1[(size_t)(k0 + k) * 64 + cl]
                : *(const float4*)&tw1[(size_t)(k0 + k) * 64 + (cl - 64)];
            *(float4*)&Bs[idx] = v4;
        }
        __syncthreads();
#pragma unroll 8
        for (int k = 0; k < 32; k += 4) {
            float4 a4[8];
#pragma unroll
            for (int i = 0; i < 8; ++i)
                a4[i] = *(const float4*)&As[(r0 + i) * 32 + k];
            float4 b4[4];
#pragma unroll
            for (int kk = 0; kk < 4; ++kk)
                b4[kk] = *(const float4*)&Bs[(k + kk) * 128 + c0];
#pragma unroll
            for (int i = 0; i < 8; ++i) {
                const float* av = (const float*)&a4[i];
#pragma unroll
                for (int kk = 0; kk < 4; ++kk) {
                    acc[i][0] += av[kk] * b4[kk].x;
                    acc[i][1] += av[kk] * b4[kk].y;
                    acc[i][2] += av[kk] * b4[kk].z;
                    acc[i][3] += av[kk] * b4[kk].w;
                }
            }
        }
    }

    bool isimp = (tc < 16);
    int lc = isimp ? c0 : (c0 - 64);
    float v[8][4];
#pragma unroll
    for (int i = 0; i < 8; ++i)
#pragma unroll
        for (int j = 0; j < 4; ++j) {
            float b = isimp ? ib1[lc + j] : tb1[lc + j];
            float x = acc[i][j] + b;
            v[i][j] = x > 0.f ? x : 0.f;
        }
#pragma unroll
    for (int i = 0; i < 8; ++i) {
        int row = i0 + r0 + i;
        if (isimp) {
#pragma unroll
            for (int c = 0; c < 3; ++c) {
                float pc = v[i][0] * iw2[(lc + 0) * 3 + c] + v[i][1] * iw2[(lc + 1) * 3 + c]
                         + v[i][2] * iw2[(lc + 2) * 3 + c] + v[i][3] * iw2[(lc + 3) * 3 + c];
#pragma unroll
                for (int off = 8; off >= 1; off >>= 1) pc += __shfl_xor(pc, off);
                if (tc == 0 && row < M) out[(size_t)row * 3 + c] = pc + ib2[c];
            }
        } else {
#pragma unroll
            for (int d = 0; d < 2; ++d) {
                float pd = v[i][0] * tw2[(lc + 0) * 2 + d] + v[i][1] * tw2[(lc + 1) * 2 + d]
                         + v[i][2] * tw2[(lc + 2) * 2 + d] + v[i][3] * tw2[(lc + 3) * 2 + d];
#pragma unroll
                for (int off = 8; off >= 1; off >>= 1) pd += __shfl_xor(pd, off);
                if (tc == 16 && row < M) {
                    float a = pd + tb2[d];
                    float sp = a > 20.f ? a : log1pf(__expf(a));
                    out[(size_t)(NN * 3) + (size_t)row * 2 + d] = sp;
                }
            }
        }
    }
}

// ---------------- gat v10r: v6 loop structure, but 2 nodes per wave (32 lanes/node,
// 4 ch/lane via uint2 gather). Every wave-instruction now serves 2 edges -> ~2x lower
// VALU issue per edge, with v6's exact memory/dependency shape (8 row-gathers in
// flight, no LDS, no cross-lane ops in the hot loop). Masked loop to max(lenA,lenB)
// (clamped index => no pad, no fallback). Lane map: hf=l>>5 (node of pair),
// lh=l&31, hd=lh>>3 (head), j=lh&7 -> channels c0=hd*32+j*4.
__global__ __launch_bounds__(256, 6) void gat_kernel(const unsigned* __restrict__ xpk,
                                                     const float* __restrict__ es,
                                                     const float* __restrict__ ed,
                                                     const int* __restrict__ rowptr,
                                                     const int* __restrict__ colidx,
                                                     float* __restrict__ h,   // in-out (residual)
                                                     const float* __restrict__ bc,
                                                     const float* __restrict__ g,
                                                     const float* __restrict__ be) {
    int wv = threadIdx.x >> 6, l = threadIdx.x & 63;
    int hf = l >> 5;                        // which node of the pair
    int lh = l & 31;
    int hd = lh >> 3;                       // head 0..3
    int j  = lh & 7;                        // 0..7
    int v = blockIdx.x * 8 + wv * 2 + hf;   // grid covers NN exactly (6250*8=50000)
    if (v >= NN) return;                    // defensive (never taken with this grid)
    int s0 = rowptr[v], s1 = rowptr[v + 1];
    int len = s1 - s0;                      // >= 1 (self-loop)
    int nmax = max(len, __shfl_xor(len, 32));
    int c0 = (hd << 5) + (j << 2);          // 4 channels owned by this lane
    int xsel = (hd << 4) + (j << 1);        // even dword index into 64-dword xpk row
    float edv = ed[((unsigned)v << 2) + hd];

    // hoisted: residual row load overlaps the whole gather loop
    float4 h4 = *(const float4*)&h[(size_t)v * 128 + c0];

    float a0 = 0.f, a1 = 0.f, a2 = 0.f, a3 = 0.f, den = 0.f;
    for (int p8 = 0; p8 < nmax; p8 += 8) {
        int u[8];
#pragma unroll
        for (int q = 0; q < 8; ++q) {
            int idx = p8 + q;
            u[q] = colidx[s0 + (idx < len ? idx : len - 1)];   // clamp: always valid mem
        }
        uint2 xw[8];
#pragma unroll
        for (int q = 0; q < 8; ++q)
            xw[q] = *(const uint2*)&xpk[((unsigned)u[q] << 6) + xsel];
        float w[8];
#pragma unroll
        for (int q = 0; q < 8; ++q) {
            float e = es[((unsigned)u[q] << 2) + hd] + edv;
            e = fmaxf(e, 0.2f * e);         // leaky_relu, slope<1 => max form
            float ww = __expf(e);           // no max-shift: softmax shift-invariant
            w[q] = (p8 + q < len) ? ww : 0.f;
            den += w[q];
        }
#pragma unroll
        for (int q = 0; q < 8; ++q) {
            float2 x0 = unpack_bf16(xw[q].x);
            float2 x1 = unpack_bf16(xw[q].y);
            a0 = fmaf(w[q], x0.x, a0);
            a1 = fmaf(w[q], x0.y, a1);
            a2 = fmaf(w[q], x1.x, a2);
            a3 = fmaf(w[q], x1.y, a3);
        }
    }
    float rd = 1.f / den;

    // ---- epilogue: residual + LN + relu; reductions within the 32-lane half.
    float4 bc4 = *(const float4*)&bc[c0];
    float y0 = a0 * rd + bc4.x + h4.x;
    float y1 = a1 * rd + bc4.y + h4.y;
    float y2 = a2 * rd + bc4.z + h4.z;
    float y3 = a3 * rd + bc4.w + h4.w;

    float s = y0 + y1 + y2 + y3;
#pragma unroll
    for (int off = 16; off >= 1; off >>= 1) s += __shfl_xor(s, off);
    float mean = s * (1.f / 128.f);
    float d0 = y0 - mean, d1 = y1 - mean, d2 = y2 - mean, d3 = y3 - mean;
    float vv = d0 * d0 + d1 * d1 + d2 * d2 + d3 * d3;
#pragma unroll
    for (int off = 16; off >= 1; off >>= 1) vv += __shfl_xor(vv, off);
    float rstd = rsqrtf(vv * (1.f / 128.f) + 1e-5f);
    float4 g4  = *(const float4*)&g[c0];
    float4 be4 = *(const float4*)&be[c0];
    float z0 = d0 * rstd * g4.x + be4.x;
    float z1 = d1 * rstd * g4.y + be4.y;
    float z2 = d2 * rstd * g4.z + be4.z;
    float z3 = d3 * rstd * g4.w + be4.w;
    float4 o;
    o.x = z0 > 0.f ? z0 : 0.f;
    o.y = z1 > 0.f ? z1 : 0.f;
    o.z = z2 > 0.f ? z2 : 0.f;
    o.w = z3 > 0.f ? z3 : 0.f;
    *(float4*)&h[(size_t)v * 128 + c0] = o;   // all 64 lanes write (2 rows per wave)
}

extern "C" void kernel_launch(void* const* d_in, const int* in_sizes, int n_in,
                              void* d_out, int out_size, void* d_ws, size_t ws_size,
                              hipStream_t stream) {
    const float* x      = (const float*)d_in[0];
    const int*   ei     = (const int*)d_in[1];
    const float* enc_w1 = (const float*)d_in[2];
    const float* enc_b1 = (const float*)d_in[3];
    const float* enc_w2 = (const float*)d_in[4];
    const float* enc_b2 = (const float*)d_in[5];
    const float *W[3], *as_[3], *ad_[3], *bc[3], *g[3], *be[3];
    for (int l = 0; l < 3; ++l) {
        W[l]   = (const float*)d_in[6 + l * 6 + 0];
        as_[l] = (const float*)d_in[6 + l * 6 + 1];
        ad_[l] = (const float*)d_in[6 + l * 6 + 2];
        bc[l]  = (const float*)d_in[6 + l * 6 + 3];
        g[l]   = (const float*)d_in[6 + l * 6 + 4];
        be[l]  = (const float*)d_in[6 + l * 6 + 5];
    }
    const float* imp_w1 = (const float*)d_in[24];
    const float* imp_b1 = (const float*)d_in[25];
    const float* imp_w2 = (const float*)d_in[26];
    const float* imp_b2 = (const float*)d_in[27];
    const float* tim_w1 = (const float*)d_in[28];
    const float* tim_b1 = (const float*)d_in[29];
    const float* tim_w2 = (const float*)d_in[30];
    const float* tim_b2 = (const float*)d_in[31];

    int* gcursor = (int*)d_ws;               // NPART
    int* rowptr  = gcursor + NPART + 64;     // NN+1
    int* colidx  = rowptr + NN + 1;          // ETOT (+8 slack)
    uintptr_t pb = (uintptr_t)(colidx + ETOT + 8);
    pb = (pb + 255) & ~(uintptr_t)255;
    unsigned* pbuf = (unsigned*)pb;          // NPART*PCAP (7.3 MB)
    uintptr_t fb = (uintptr_t)(pbuf + (size_t)NPART * PCAP);
    fb = (fb + 255) & ~(uintptr_t)255;
    float* es = (float*)fb;                  // NN*4
    float* ed = es + (size_t)NN * 4;         // NN*4
    float* h  = ed + (size_t)NN * 4;         // NN*128 fp32
    float* xpf = h + (size_t)NN * 128;       // region sized NN*128 floats
    unsigned* xpk = (unsigned*)xpf;          // packed bf16 uses first half
    float* tmp = xpf;                        // enc1 scratch aliases (dead before xpk lives)

    hipMemsetAsync(gcursor, 0, NPART * sizeof(int), stream);
    pass1_kernel<<<512, 256, 0, stream>>>(ei, gcursor, pbuf);
    pass2_kernel<<<NPART, 256, 0, stream>>>(pbuf, gcursor, rowptr, colidx);

    const int GB64 = (NN + 63) / 64;
    gemm_small_kernel<128, true><<<(NN + 31) / 32, 256, 0, stream>>>(x, enc_w1, enc_b1, tmp, NN, FINDIM);
    gemm128_kernel<true, false><<<GB64, 256, 0, stream>>>(tmp, enc_w2, enc_b2, h, nullptr,
                                                          nullptr, nullptr, nullptr, nullptr, NN);

    for (int l = 0; l < 3; ++l) {
        gemm128_kernel<false, true><<<GB64, 256, 0, stream>>>(h, W[l], nullptr, nullptr, xpk,
                                                              as_[l], ad_[l], es, ed, NN);
        gat_kernel<<<(NN + 7) / 8, 256, 0, stream>>>(xpk, es, ed, rowptr, colidx, h,
                                                     bc[l], g[l], be[l]);
    }

    gemm_heads_kernel<<<GB64, 256, 0, stream>>>(h, imp_w1, imp_b1, tim_w1, tim_b1,
                                                imp_w2, imp_b2, tim_w2, tim_b2,
                                                (float*)d_out, NN);
}